// Round 12
// baseline (303.746 us; speedup 1.0000x reference)
//
#include <hip/hip_runtime.h>

#define DD 128
#define CC 64
#define BKW 512            // nodes per bucket
#define NPB 4096           // edges per phase-B block

typedef __attribute__((ext_vector_type(8))) short short8v;
typedef __attribute__((ext_vector_type(4))) float f32x4;
typedef __attribute__((ext_vector_type(2))) float f32x2;

static __device__ inline ushort f2bf_rne(float f) {
    unsigned u = __float_as_uint(f);
    unsigned r = (u + 0x7FFFu + ((u >> 16) & 1u)) >> 16;
    return (ushort)r;
}
static __device__ inline float bf2f(ushort h) {
    return __uint_as_float(((unsigned)h) << 16);
}
static __device__ inline float bflo(uint u) {
    return __uint_as_float(u << 16);
}
static __device__ inline float bfhi(uint u) {
    return __uint_as_float(u & 0xffff0000u);
}

// ============ bucket histogram: per-block LDS hist, 256 global atomics ======
__global__ __launch_bounds__(256) void bucket_cnt_kernel(const int* __restrict__ ei,
                                                         int* __restrict__ bcnt, int E) {
    __shared__ int h[256];
    const int t = threadIdx.x;
    h[t] = 0;
    __syncthreads();
    const int base = blockIdx.x * 8192;
    const int end = min(E, base + 8192);
    for (int j = base + t; j < end; j += 256) {
        atomicAdd(&h[ei[E + j] >> 9], 1);
    }
    __syncthreads();
    if (h[t]) atomicAdd(&bcnt[t], h[t]);
}

// ============ bucket scan (256 entries, 1 block) -> boffs[257], bcur ========
__global__ __launch_bounds__(256) void bucket_scan_kernel(const int* __restrict__ bcnt,
                                                          int* __restrict__ boffs,
                                                          int* __restrict__ bcur) {
    __shared__ int s[256];
    const int t = threadIdx.x;
    int v = bcnt[t];
    s[t] = v;
    __syncthreads();
    for (int off = 1; off < 256; off <<= 1) {
        int xv = 0;
        if (t >= off) xv = s[t - off];
        __syncthreads();
        if (t >= off) s[t] += xv;
        __syncthreads();
    }
    int excl = s[t] - v;
    boffs[t] = excl;
    bcur[t] = excl;
    if (t == 255) boffs[256] = s[255];
}

// ================= phase B: bin edges by bucket =================
__global__ __launch_bounds__(256) void binA_kernel(const int* __restrict__ ei,
                                                   int* __restrict__ bcur,
                                                   uint2* __restrict__ ebuf, int E) {
    __shared__ int sRun[256];
    __shared__ int sRel[256];
    __shared__ int sBase[256];
    __shared__ uint2 sPair[NPB];
    __shared__ int sHist[256];
    const int t = threadIdx.x;
    const int e0 = blockIdx.x * NPB;
    const int cntE = min(NPB, E - e0);

    sHist[t] = 0;
    __syncthreads();
    for (int j = t; j < cntE; j += 256) {
        int dst = ei[E + e0 + j];
        atomicAdd(&sHist[dst >> 9], 1);
    }
    __syncthreads();
    int h = sHist[t];
    sRun[t] = h;
    __syncthreads();
    for (int off = 1; off < 256; off <<= 1) {
        int v = 0;
        if (t >= off) v = sRun[t - off];
        __syncthreads();
        if (t >= off) sRun[t] += v;
        __syncthreads();
    }
    int runstart = sRun[t] - h;
    int base = 0;
    if (h > 0) base = atomicAdd(&bcur[t], h);
    sRun[t] = runstart;
    sRel[t] = runstart;
    sBase[t] = base;
    __syncthreads();
    for (int j = t; j < cntE; j += 256) {
        int src = ei[e0 + j];
        int dst = ei[E + e0 + j];
        int b = dst >> 9;
        int slot = atomicAdd(&sRel[b], 1);
        sPair[slot] = make_uint2((unsigned)src, (unsigned)dst);
    }
    __syncthreads();
    for (int s = t; s < cntE; s += 256) {
        uint2 p = sPair[s];
        int b = (int)(p.y >> 9);
        int gpos = sBase[b] + (s - sRun[b]);
        ebuf[gpos] = p;
    }
}

// ====== phase C: per-bucket: derive per-node cnt/offs in LDS, then scatter ====
__global__ __launch_bounds__(256) void binB2_kernel(const uint2* __restrict__ ebuf,
                                                    const int* __restrict__ boffs,
                                                    int* __restrict__ offs,
                                                    int* __restrict__ cnt,
                                                    int* __restrict__ csr, int n) {
    __shared__ int sCnt[BKW];
    __shared__ int sOffs[BKW];
    __shared__ int sScan[256];
    const int t = threadIdx.x;
    const int node0 = blockIdx.x * BKW;
    const int start = boffs[blockIdx.x];
    const int end = boffs[blockIdx.x + 1];

    sCnt[t] = 0; sCnt[t + 256] = 0;
    __syncthreads();
    for (int j = start + t; j < end; j += 256) {
        int d = (int)ebuf[j].y - node0;
        atomicAdd(&sCnt[d], 1);
    }
    __syncthreads();
    int v0 = sCnt[2 * t], v1 = sCnt[2 * t + 1];
    int sum = v0 + v1;
    sScan[t] = sum;
    __syncthreads();
    for (int off = 1; off < 256; off <<= 1) {
        int xv = 0;
        if (t >= off) xv = sScan[t - off];
        __syncthreads();
        if (t >= off) sScan[t] += xv;
        __syncthreads();
    }
    int excl = sScan[t] - sum;
    sOffs[2 * t] = start + excl;
    sOffs[2 * t + 1] = start + excl + v0;
    __syncthreads();
    for (int i = t; i < BKW; i += 256) {
        int node = node0 + i;
        if (node < n) { offs[node] = sOffs[i]; cnt[node] = sCnt[i]; }
    }
    __syncthreads();
    sCnt[t] = 0; sCnt[t + 256] = 0;
    __syncthreads();
    for (int j = start + t; j < end; j += 256) {
        uint2 p = ebuf[j];
        int d = (int)p.y - node0;
        int r = atomicAdd(&sCnt[d], 1);
        csr[sOffs[d] + r] = (int)p.x;
    }
}

// ================= f32 -> bf16 hi plane =================
__global__ __launch_bounds__(256) void xsplit_kernel(const float* __restrict__ x,
                                                     ushort* __restrict__ xh,
                                                     int total8) {
    int i = blockIdx.x * 256 + threadIdx.x;
    if (i >= total8) return;
    float4 a = ((const float4*)x)[2 * i];
    float4 b = ((const float4*)x)[2 * i + 1];
    ushort r[8] = {f2bf_rne(a.x), f2bf_rne(a.y), f2bf_rne(a.z), f2bf_rne(a.w),
                   f2bf_rne(b.x), f2bf_rne(b.y), f2bf_rne(b.z), f2bf_rne(b.w)};
    uint4 o;
    o.x = (uint)r[0] | ((uint)r[1] << 16);
    o.y = (uint)r[2] | ((uint)r[3] << 16);
    o.z = (uint)r[4] | ((uint)r[5] << 16);
    o.w = (uint)r[6] | ((uint)r[7] << 16);
    ((uint4*)xh)[i] = o;
}

// ====== CSR gather-aggregate: up to 16 neighbors in flight, f32x2 accum =====
__global__ __launch_bounds__(256) void csr_agg4_kernel(
    const ushort* __restrict__ xh, const int* __restrict__ offs,
    const int* __restrict__ cnt, const int* __restrict__ csr,
    ushort* __restrict__ meanH, int n) {
    int node = blockIdx.x * 4 + (threadIdx.x >> 6);
    if (node >= n) return;
    const int lane = threadIdx.x & 63;
    const int sub = lane >> 4;
    const int li = lane & 15;
    const int start = offs[node];
    const int c = cnt[node];
    f32x2 a[4], aa[4];
    #pragma unroll
    for (int k = 0; k < 4; ++k) { a[k] = (f32x2){0.f, 0.f}; aa[k] = (f32x2){0.f, 0.f}; }
    #define ACC4(A, U) \
        A[0] += (f32x2){bflo(U.x), bfhi(U.x)}; \
        A[1] += (f32x2){bflo(U.y), bfhi(U.y)}; \
        A[2] += (f32x2){bflo(U.z), bfhi(U.z)}; \
        A[3] += (f32x2){bflo(U.w), bfhi(U.w)};
    const int c16 = c & ~15;
    int j = 0;
    if (c16 > 0) {
        int s0 = csr[start + sub];
        int s1 = csr[start + 4 + sub];
        int s2 = csr[start + 8 + sub];
        int s3 = csr[start + 12 + sub];
        for (; j < c16; j += 16) {
            int t0 = 0, t1 = 0, t2 = 0, t3 = 0;
            if (j + 16 < c16) {
                t0 = csr[start + j + 16 + sub];
                t1 = csr[start + j + 20 + sub];
                t2 = csr[start + j + 24 + sub];
                t3 = csr[start + j + 28 + sub];
            }
            uint4 u0 = *(const uint4*)(xh + (size_t)s0 * DD + li * 8);
            uint4 u1 = *(const uint4*)(xh + (size_t)s1 * DD + li * 8);
            uint4 u2 = *(const uint4*)(xh + (size_t)s2 * DD + li * 8);
            uint4 u3 = *(const uint4*)(xh + (size_t)s3 * DD + li * 8);
            ACC4(a, u0); ACC4(a, u1); ACC4(aa, u2); ACC4(aa, u3);
            s0 = t0; s1 = t1; s2 = t2; s3 = t3;
        }
    }
    if (c - j >= 8) {
        int s0 = csr[start + j + sub];
        int s1 = csr[start + j + 4 + sub];
        uint4 u0 = *(const uint4*)(xh + (size_t)s0 * DD + li * 8);
        uint4 u1 = *(const uint4*)(xh + (size_t)s1 * DD + li * 8);
        ACC4(a, u0); ACC4(aa, u1);
        j += 8;
    }
    if (c - j >= 4) {
        int s = csr[start + j + sub];
        uint4 u = *(const uint4*)(xh + (size_t)s * DD + li * 8);
        ACC4(a, u);
        j += 4;
    }
    if (j + sub < c) {
        int s = csr[start + j + sub];
        uint4 u = *(const uint4*)(xh + (size_t)s * DD + li * 8);
        ACC4(aa, u);
    }
    #undef ACC4
    float res[8];
    #pragma unroll
    for (int k = 0; k < 4; ++k) {
        f32x2 v = a[k] + aa[k];
        float e0 = v.x; e0 += __shfl_xor(e0, 16); e0 += __shfl_xor(e0, 32);
        float e1 = v.y; e1 += __shfl_xor(e1, 16); e1 += __shfl_xor(e1, 32);
        res[2 * k] = e0; res[2 * k + 1] = e1;
    }
    if (sub == 0) {
        float inv = 1.0f / fmaxf((float)c, 1.0f);
        short8v o;
        #pragma unroll
        for (int k = 0; k < 8; ++k) o[k] = (short)f2bf_rne(res[k] * inv);
        *(short8v*)(meanH + (size_t)node * DD + li * 8) = o;
    }
}

// ====== weight prep: MFMA-frag layout =================================
__global__ __launch_bounds__(256) void wfrag_kernel(
    const float* __restrict__ Wl1, const float* __restrict__ Wr1,
    const float* __restrict__ Wl2, const float* __restrict__ Wr2,
    ushort* __restrict__ WTfrag1, ushort* __restrict__ WTfrag2) {
    int idx = blockIdx.x * 256 + threadIdx.x;     // [0, 8192)
    if (idx >= 8192) return;
    const float* Wl = blockIdx.y ? Wl2 : Wl1;
    const float* Wr = blockIdx.y ? Wr2 : Wr1;
    ushort* dst = (blockIdx.y ? WTfrag2 : WTfrag1) + (size_t)idx * 8;
    int lane = idx & 63, p = (idx >> 6) & 1, t = (idx >> 7) & 7, s = idx >> 10;
    int col = t * 16 + (lane & 15);
    int k0 = s * 32 + (lane >> 4) * 8;
    #pragma unroll
    for (int j = 0; j < 8; ++j) {
        int k = k0 + j;
        float v = (k < DD) ? Wl[k * DD + col] : Wr[(k - DD) * DD + col];
        ushort h = f2bf_rne(v);
        dst[j] = p ? f2bf_rne(v - bf2f(h)) : h;
    }
}

__global__ __launch_bounds__(256) void wofrag_kernel(const float* __restrict__ Wout,
                                                     ushort* __restrict__ WoFrag) {
    int idx = blockIdx.x * 256 + threadIdx.x;     // [0, 2048)
    if (idx >= 2048) return;
    ushort* dst = WoFrag + (size_t)idx * 8;
    int lane = idx & 63, p = (idx >> 6) & 1, t = (idx >> 7) & 3, kc = idx >> 9;
    int col = t * 16 + (lane & 15);
    int k0 = kc * 32 + (lane >> 4) * 8;
    #pragma unroll
    for (int j = 0; j < 8; ++j) {
        float v = Wout[(k0 + j) * CC + col];
        ushort h = f2bf_rne(v);
        dst[j] = p ? f2bf_rne(v - bf2f(h)) : h;
    }
}

// ================= MFMA SAGE layer: 128 rows/block, 2 row-tiles/wave ========
// B-frag loads (coalesced 1KB wave reads, L2-hot) amortized over 2 row-tiles.
// No LDS / no barriers in the main loop. PROJ adds a wave-local LDS transpose.
template <bool PROJ>
__global__ __launch_bounds__(256) void layer_mfma_kernel(
    const ushort* __restrict__ meanH, const ushort* __restrict__ rootH,
    const ushort* __restrict__ WTfrag, const float* __restrict__ bias,
    ushort* __restrict__ outH,
    const ushort* __restrict__ WoFrag, const float* __restrict__ bout,
    float* __restrict__ outF, int n) {
    __shared__ ushort sH[PROJ ? 128 : 1][136];   // stride 272B: 2-way max aliasing
    const int tid = threadIdx.x;
    const int w = tid >> 6;
    const int l = tid & 63;
    const int row0 = blockIdx.x * 128;
    const int lrow = w * 16 + (l & 15);
    const int kb = (l >> 4) * 8;
    const int lcol = l & 15;
    const int arowg0 = min(row0 + lrow, n - 1);
    const int arowg1 = min(row0 + 64 + lrow, n - 1);

    const ushort* Am0 = meanH + (size_t)arowg0 * DD;
    const ushort* Ar0 = rootH + (size_t)arowg0 * DD;
    const ushort* Am1 = meanH + (size_t)arowg1 * DD;
    const ushort* Ar1 = rootH + (size_t)arowg1 * DD;

    f32x4 acc0[8], acc1[8];
    #pragma unroll
    for (int t = 0; t < 8; ++t) {
        acc0[t] = (f32x4){0.f, 0.f, 0.f, 0.f};
        acc1[t] = (f32x4){0.f, 0.f, 0.f, 0.f};
    }

    #pragma unroll
    for (int s = 0; s < 8; ++s) {
        short8v ah0 = (s < 4) ? *(const short8v*)(Am0 + s * 32 + kb)
                              : *(const short8v*)(Ar0 + (s - 4) * 32 + kb);
        short8v ah1 = (s < 4) ? *(const short8v*)(Am1 + s * 32 + kb)
                              : *(const short8v*)(Ar1 + (s - 4) * 32 + kb);
        const ushort* fb = WTfrag + (size_t)s * 8192 + l * 8;
        #pragma unroll
        for (int t = 0; t < 8; ++t) {
            short8v bh = *(const short8v*)(fb + t * 1024);
            short8v bl = *(const short8v*)(fb + t * 1024 + 512);
            acc0[t] = __builtin_amdgcn_mfma_f32_16x16x32_bf16(ah0, bh, acc0[t], 0, 0, 0);
            acc0[t] = __builtin_amdgcn_mfma_f32_16x16x32_bf16(ah0, bl, acc0[t], 0, 0, 0);
            acc1[t] = __builtin_amdgcn_mfma_f32_16x16x32_bf16(ah1, bh, acc1[t], 0, 0, 0);
            acc1[t] = __builtin_amdgcn_mfma_f32_16x16x32_bf16(ah1, bl, acc1[t], 0, 0, 0);
        }
    }

    // C/D layout: col = t*16 + (lane&15), row = w*16 + 4*(lane>>4) + reg
    const int lrow0 = w * 16 + (l >> 4) * 4;
    if (!PROJ) {
        #pragma unroll
        for (int t = 0; t < 8; ++t) {
            const int col = t * 16 + lcol;
            const float b = bias[col];
            #pragma unroll
            for (int r = 0; r < 4; ++r) {
                int row = row0 + lrow0 + r;
                if (row < n)
                    outH[(size_t)row * DD + col] = f2bf_rne(fmaxf(acc0[t][r] + b, 0.f));
                int row2 = row0 + 64 + lrow0 + r;
                if (row2 < n)
                    outH[(size_t)row2 * DD + col] = f2bf_rne(fmaxf(acc1[t][r] + b, 0.f));
            }
        }
    } else {
        // wave-local transpose of h2 through sH (wave writes+reads only its rows)
        #pragma unroll
        for (int t = 0; t < 8; ++t) {
            const int col = t * 16 + lcol;
            const float b = bias[col];
            #pragma unroll
            for (int r = 0; r < 4; ++r) {
                sH[lrow0 + r][col]      = f2bf_rne(fmaxf(acc0[t][r] + b, 0.f));
                sH[64 + lrow0 + r][col] = f2bf_rne(fmaxf(acc1[t][r] + b, 0.f));
            }
        }
        __syncthreads();
        f32x4 po0[4], po1[4];
        #pragma unroll
        for (int t = 0; t < 4; ++t) {
            po0[t] = (f32x4){0.f, 0.f, 0.f, 0.f};
            po1[t] = (f32x4){0.f, 0.f, 0.f, 0.f};
        }
        #pragma unroll
        for (int kc = 0; kc < 4; ++kc) {
            short8v ah0 = *(const short8v*)&sH[lrow][kc * 32 + kb];
            short8v ah1 = *(const short8v*)&sH[64 + lrow][kc * 32 + kb];
            const ushort* fb = WoFrag + (size_t)kc * 4096 + l * 8;
            #pragma unroll
            for (int t = 0; t < 4; ++t) {
                short8v bh = *(const short8v*)(fb + t * 1024);
                short8v bl = *(const short8v*)(fb + t * 1024 + 512);
                po0[t] = __builtin_amdgcn_mfma_f32_16x16x32_bf16(ah0, bh, po0[t], 0, 0, 0);
                po0[t] = __builtin_amdgcn_mfma_f32_16x16x32_bf16(ah0, bl, po0[t], 0, 0, 0);
                po1[t] = __builtin_amdgcn_mfma_f32_16x16x32_bf16(ah1, bh, po1[t], 0, 0, 0);
                po1[t] = __builtin_amdgcn_mfma_f32_16x16x32_bf16(ah1, bl, po1[t], 0, 0, 0);
            }
        }
        #pragma unroll
        for (int t = 0; t < 4; ++t) {
            const int col = t * 16 + lcol;
            const float b = bout[col];
            #pragma unroll
            for (int r = 0; r < 4; ++r) {
                int row = row0 + lrow0 + r;
                if (row < n) outF[(size_t)row * CC + col] = po0[t][r] + b;
                int row2 = row0 + 64 + lrow0 + r;
                if (row2 < n) outF[(size_t)row2 * CC + col] = po1[t][r] + b;
            }
        }
    }
}

extern "C" void kernel_launch(void* const* d_in, const int* in_sizes, int n_in,
                              void* d_out, int out_size, void* d_ws, size_t ws_size,
                              hipStream_t stream) {
    const float* x    = (const float*)d_in[0];
    const int*   ei   = (const int*)d_in[1];
    const float* W1l  = (const float*)d_in[2];
    const float* b1   = (const float*)d_in[3];
    const float* W1r  = (const float*)d_in[4];
    const float* W2l  = (const float*)d_in[5];
    const float* b2   = (const float*)d_in[6];
    const float* W2r  = (const float*)d_in[7];
    const float* Wout = (const float*)d_in[8];
    const float* bout = (const float*)d_in[9];
    float* out = (float*)d_out;
    const int n = in_sizes[0] / DD;       // 100000
    const int E = in_sizes[1] / 2;        // 1600000
    const size_t NP = (size_t)n * DD;

    const int NBUCK = (n + BKW - 1) / BKW;

    // workspace layout
    int* cnt   = (int*)d_ws;                              // 100352
    int* offs  = cnt + 100352;                            // 100352
    int* bcnt  = offs + 100352;                           // 256
    int* boffs = bcnt + 256;                              // 257 (pad 512)
    int* bcur  = boffs + 512;                             // 256
    int* csr   = bcur + 256;                              // E (pad)
    uint2* ebuf = (uint2*)(csr + 1600256);                // E pairs (12.8MB)
    ushort* xh  = (ushort*)ebuf;                          // union: n*128 bf16 (25.6MB)
    ushort* meanH = xh + NP;                              // n*128 bf16
    ushort* h1h = meanH + NP;                             // n*128 bf16
    ushort* WTfrag1 = h1h + NP;                           // 65536 ushorts each
    ushort* WTfrag2 = WTfrag1 + 65536;
    ushort* WoFrag  = WTfrag2 + 65536;                    // 16384 ushorts

    hipMemsetAsync(bcnt, 0, sizeof(int) * 256, stream);
    bucket_cnt_kernel<<<(E + 8191) / 8192, 256, 0, stream>>>(ei, bcnt, E);
    bucket_scan_kernel<<<1, 256, 0, stream>>>(bcnt, boffs, bcur);
    binA_kernel<<<(E + NPB - 1) / NPB, 256, 0, stream>>>(ei, bcur, ebuf, E);
    binB2_kernel<<<NBUCK, 256, 0, stream>>>(ebuf, boffs, offs, cnt, csr, n);

    dim3 wgrid(32, 2);
    wfrag_kernel<<<wgrid, 256, 0, stream>>>(W1l, W1r, W2l, W2r, WTfrag1, WTfrag2);
    wofrag_kernel<<<8, 256, 0, stream>>>(Wout, WoFrag);

    // ebuf dead now -> reuse region as xh
    xsplit_kernel<<<(n * DD / 8 + 255) / 256, 256, 0, stream>>>(x, xh, n * DD / 8);

    const int nblk = (n + 127) / 128;
    const int ablk = (n + 3) / 4;

    csr_agg4_kernel<<<ablk, 256, 0, stream>>>(xh, offs, cnt, csr, meanH, n);
    layer_mfma_kernel<false><<<nblk, 256, 0, stream>>>(
        meanH, xh, WTfrag1, b1, h1h,
        (const ushort*)nullptr, (const float*)nullptr, (float*)nullptr, n);

    csr_agg4_kernel<<<ablk, 256, 0, stream>>>(h1h, offs, cnt, csr, meanH, n);
    layer_mfma_kernel<true><<<nblk, 256, 0, stream>>>(
        meanH, h1h, WTfrag2, b2, (ushort*)nullptr,
        WoFrag, bout, out, n);
}

// Round 13
// 260.817 us; speedup vs baseline: 1.1646x; 1.1646x over previous
//
#include <hip/hip_runtime.h>

#define DD 128
#define CC 64
#define BKW 512            // nodes per bucket
#define NPB 4096           // edges per phase-B block

typedef __attribute__((ext_vector_type(8))) short short8v;
typedef __attribute__((ext_vector_type(4))) float f32x4;
typedef __attribute__((ext_vector_type(2))) float f32x2;

static __device__ inline ushort f2bf_rne(float f) {
    unsigned u = __float_as_uint(f);
    unsigned r = (u + 0x7FFFu + ((u >> 16) & 1u)) >> 16;
    return (ushort)r;
}
static __device__ inline float bf2f(ushort h) {
    return __uint_as_float(((unsigned)h) << 16);
}
static __device__ inline float bflo(uint u) {
    return __uint_as_float(u << 16);
}
static __device__ inline float bfhi(uint u) {
    return __uint_as_float(u & 0xffff0000u);
}

// ============ bucket histogram: per-block LDS hist, 256 global atomics ======
__global__ __launch_bounds__(256) void bucket_cnt_kernel(const int* __restrict__ ei,
                                                         int* __restrict__ bcnt, int E) {
    __shared__ int h[256];
    const int t = threadIdx.x;
    h[t] = 0;
    __syncthreads();
    const int base = blockIdx.x * 8192;
    const int end = min(E, base + 8192);
    for (int j = base + t; j < end; j += 256) {
        atomicAdd(&h[ei[E + j] >> 9], 1);
    }
    __syncthreads();
    if (h[t]) atomicAdd(&bcnt[t], h[t]);
}

// ============ bucket scan (256 entries, 1 block) -> boffs[257], bcur ========
__global__ __launch_bounds__(256) void bucket_scan_kernel(const int* __restrict__ bcnt,
                                                          int* __restrict__ boffs,
                                                          int* __restrict__ bcur) {
    __shared__ int s[256];
    const int t = threadIdx.x;
    int v = bcnt[t];
    s[t] = v;
    __syncthreads();
    for (int off = 1; off < 256; off <<= 1) {
        int xv = 0;
        if (t >= off) xv = s[t - off];
        __syncthreads();
        if (t >= off) s[t] += xv;
        __syncthreads();
    }
    int excl = s[t] - v;
    boffs[t] = excl;
    bcur[t] = excl;
    if (t == 255) boffs[256] = s[255];
}

// ================= phase B: bin edges by bucket =================
__global__ __launch_bounds__(256) void binA_kernel(const int* __restrict__ ei,
                                                   int* __restrict__ bcur,
                                                   uint2* __restrict__ ebuf, int E) {
    __shared__ int sRun[256];
    __shared__ int sRel[256];
    __shared__ int sBase[256];
    __shared__ uint2 sPair[NPB];
    __shared__ int sHist[256];
    const int t = threadIdx.x;
    const int e0 = blockIdx.x * NPB;
    const int cntE = min(NPB, E - e0);

    sHist[t] = 0;
    __syncthreads();
    for (int j = t; j < cntE; j += 256) {
        int dst = ei[E + e0 + j];
        atomicAdd(&sHist[dst >> 9], 1);
    }
    __syncthreads();
    int h = sHist[t];
    sRun[t] = h;
    __syncthreads();
    for (int off = 1; off < 256; off <<= 1) {
        int v = 0;
        if (t >= off) v = sRun[t - off];
        __syncthreads();
        if (t >= off) sRun[t] += v;
        __syncthreads();
    }
    int runstart = sRun[t] - h;
    int base = 0;
    if (h > 0) base = atomicAdd(&bcur[t], h);
    sRun[t] = runstart;
    sRel[t] = runstart;
    sBase[t] = base;
    __syncthreads();
    for (int j = t; j < cntE; j += 256) {
        int src = ei[e0 + j];
        int dst = ei[E + e0 + j];
        int b = dst >> 9;
        int slot = atomicAdd(&sRel[b], 1);
        sPair[slot] = make_uint2((unsigned)src, (unsigned)dst);
    }
    __syncthreads();
    for (int s = t; s < cntE; s += 256) {
        uint2 p = sPair[s];
        int b = (int)(p.y >> 9);
        int gpos = sBase[b] + (s - sRun[b]);
        ebuf[gpos] = p;
    }
}

// ====== phase C: per-bucket: derive per-node cnt/offs in LDS, then scatter ====
__global__ __launch_bounds__(256) void binB2_kernel(const uint2* __restrict__ ebuf,
                                                    const int* __restrict__ boffs,
                                                    int* __restrict__ offs,
                                                    int* __restrict__ cnt,
                                                    int* __restrict__ csr, int n) {
    __shared__ int sCnt[BKW];
    __shared__ int sOffs[BKW];
    __shared__ int sScan[256];
    const int t = threadIdx.x;
    const int node0 = blockIdx.x * BKW;
    const int start = boffs[blockIdx.x];
    const int end = boffs[blockIdx.x + 1];

    sCnt[t] = 0; sCnt[t + 256] = 0;
    __syncthreads();
    for (int j = start + t; j < end; j += 256) {
        int d = (int)ebuf[j].y - node0;
        atomicAdd(&sCnt[d], 1);
    }
    __syncthreads();
    int v0 = sCnt[2 * t], v1 = sCnt[2 * t + 1];
    int sum = v0 + v1;
    sScan[t] = sum;
    __syncthreads();
    for (int off = 1; off < 256; off <<= 1) {
        int xv = 0;
        if (t >= off) xv = sScan[t - off];
        __syncthreads();
        if (t >= off) sScan[t] += xv;
        __syncthreads();
    }
    int excl = sScan[t] - sum;
    sOffs[2 * t] = start + excl;
    sOffs[2 * t + 1] = start + excl + v0;
    __syncthreads();
    for (int i = t; i < BKW; i += 256) {
        int node = node0 + i;
        if (node < n) { offs[node] = sOffs[i]; cnt[node] = sCnt[i]; }
    }
    __syncthreads();
    sCnt[t] = 0; sCnt[t + 256] = 0;
    __syncthreads();
    for (int j = start + t; j < end; j += 256) {
        uint2 p = ebuf[j];
        int d = (int)p.y - node0;
        int r = atomicAdd(&sCnt[d], 1);
        csr[sOffs[d] + r] = (int)p.x;
    }
}

// ================= f32 -> bf16 hi plane =================
__global__ __launch_bounds__(256) void xsplit_kernel(const float* __restrict__ x,
                                                     ushort* __restrict__ xh,
                                                     int total8) {
    int i = blockIdx.x * 256 + threadIdx.x;
    if (i >= total8) return;
    float4 a = ((const float4*)x)[2 * i];
    float4 b = ((const float4*)x)[2 * i + 1];
    ushort r[8] = {f2bf_rne(a.x), f2bf_rne(a.y), f2bf_rne(a.z), f2bf_rne(a.w),
                   f2bf_rne(b.x), f2bf_rne(b.y), f2bf_rne(b.z), f2bf_rne(b.w)};
    uint4 o;
    o.x = (uint)r[0] | ((uint)r[1] << 16);
    o.y = (uint)r[2] | ((uint)r[3] << 16);
    o.z = (uint)r[4] | ((uint)r[5] << 16);
    o.w = (uint)r[6] | ((uint)r[7] << 16);
    ((uint4*)xh)[i] = o;
}

// ====== CSR gather-aggregate: up to 16 neighbors in flight, f32x2 accum =====
__global__ __launch_bounds__(256) void csr_agg4_kernel(
    const ushort* __restrict__ xh, const int* __restrict__ offs,
    const int* __restrict__ cnt, const int* __restrict__ csr,
    ushort* __restrict__ meanH, int n) {
    int node = blockIdx.x * 4 + (threadIdx.x >> 6);
    if (node >= n) return;
    const int lane = threadIdx.x & 63;
    const int sub = lane >> 4;
    const int li = lane & 15;
    const int start = offs[node];
    const int c = cnt[node];
    f32x2 a[4], aa[4];
    #pragma unroll
    for (int k = 0; k < 4; ++k) { a[k] = (f32x2){0.f, 0.f}; aa[k] = (f32x2){0.f, 0.f}; }
    #define ACC4(A, U) \
        A[0] += (f32x2){bflo(U.x), bfhi(U.x)}; \
        A[1] += (f32x2){bflo(U.y), bfhi(U.y)}; \
        A[2] += (f32x2){bflo(U.z), bfhi(U.z)}; \
        A[3] += (f32x2){bflo(U.w), bfhi(U.w)};
    const int c16 = c & ~15;
    int j = 0;
    if (c16 > 0) {
        int s0 = csr[start + sub];
        int s1 = csr[start + 4 + sub];
        int s2 = csr[start + 8 + sub];
        int s3 = csr[start + 12 + sub];
        for (; j < c16; j += 16) {
            int t0 = 0, t1 = 0, t2 = 0, t3 = 0;
            if (j + 16 < c16) {
                t0 = csr[start + j + 16 + sub];
                t1 = csr[start + j + 20 + sub];
                t2 = csr[start + j + 24 + sub];
                t3 = csr[start + j + 28 + sub];
            }
            uint4 u0 = *(const uint4*)(xh + (size_t)s0 * DD + li * 8);
            uint4 u1 = *(const uint4*)(xh + (size_t)s1 * DD + li * 8);
            uint4 u2 = *(const uint4*)(xh + (size_t)s2 * DD + li * 8);
            uint4 u3 = *(const uint4*)(xh + (size_t)s3 * DD + li * 8);
            ACC4(a, u0); ACC4(a, u1); ACC4(aa, u2); ACC4(aa, u3);
            s0 = t0; s1 = t1; s2 = t2; s3 = t3;
        }
    }
    if (c - j >= 8) {
        int s0 = csr[start + j + sub];
        int s1 = csr[start + j + 4 + sub];
        uint4 u0 = *(const uint4*)(xh + (size_t)s0 * DD + li * 8);
        uint4 u1 = *(const uint4*)(xh + (size_t)s1 * DD + li * 8);
        ACC4(a, u0); ACC4(aa, u1);
        j += 8;
    }
    if (c - j >= 4) {
        int s = csr[start + j + sub];
        uint4 u = *(const uint4*)(xh + (size_t)s * DD + li * 8);
        ACC4(a, u);
        j += 4;
    }
    if (j + sub < c) {
        int s = csr[start + j + sub];
        uint4 u = *(const uint4*)(xh + (size_t)s * DD + li * 8);
        ACC4(aa, u);
    }
    #undef ACC4
    float res[8];
    #pragma unroll
    for (int k = 0; k < 4; ++k) {
        f32x2 v = a[k] + aa[k];
        float e0 = v.x; e0 += __shfl_xor(e0, 16); e0 += __shfl_xor(e0, 32);
        float e1 = v.y; e1 += __shfl_xor(e1, 16); e1 += __shfl_xor(e1, 32);
        res[2 * k] = e0; res[2 * k + 1] = e1;
    }
    if (sub == 0) {
        float inv = 1.0f / fmaxf((float)c, 1.0f);
        short8v o;
        #pragma unroll
        for (int k = 0; k < 8; ++k) o[k] = (short)f2bf_rne(res[k] * inv);
        *(short8v*)(meanH + (size_t)node * DD + li * 8) = o;
    }
}

// ====== weight prep: single-plane bf16 MFMA-frag layout ======
// WTfrag[s][t][lane][8]: s=k-slice(8), t=col-tile(8), lane=64.
// value = WT[col = t*16+(lane&15)][k = s*32+(lane>>4)*8+j] rounded to bf16.
__global__ __launch_bounds__(256) void wfrag_kernel(
    const float* __restrict__ Wl1, const float* __restrict__ Wr1,
    const float* __restrict__ Wl2, const float* __restrict__ Wr2,
    ushort* __restrict__ WTfrag1, ushort* __restrict__ WTfrag2) {
    int idx = blockIdx.x * 256 + threadIdx.x;     // [0, 4096)
    if (idx >= 4096) return;
    const float* Wl = blockIdx.y ? Wl2 : Wl1;
    const float* Wr = blockIdx.y ? Wr2 : Wr1;
    ushort* dst = (blockIdx.y ? WTfrag2 : WTfrag1) + (size_t)idx * 8;
    int lane = idx & 63, t = (idx >> 6) & 7, s = idx >> 9;
    int col = t * 16 + (lane & 15);
    int k0 = s * 32 + (lane >> 4) * 8;
    #pragma unroll
    for (int j = 0; j < 8; ++j) {
        int k = k0 + j;
        float v = (k < DD) ? Wl[k * DD + col] : Wr[(k - DD) * DD + col];
        dst[j] = f2bf_rne(v);
    }
}

// WoFrag[kc][t][lane][8]: kc=k-slice(4), t=col-tile(4); Wout is [128][64].
__global__ __launch_bounds__(256) void wofrag_kernel(const float* __restrict__ Wout,
                                                     ushort* __restrict__ WoFrag) {
    int idx = blockIdx.x * 256 + threadIdx.x;     // [0, 1024)
    if (idx >= 1024) return;
    ushort* dst = WoFrag + (size_t)idx * 8;
    int lane = idx & 63, t = (idx >> 6) & 3, kc = idx >> 8;
    int col = t * 16 + (lane & 15);
    int k0 = kc * 32 + (lane >> 4) * 8;
    #pragma unroll
    for (int j = 0; j < 8; ++j) {
        dst[j] = f2bf_rne(Wout[(k0 + j) * CC + col]);
    }
}

// ================= MFMA SAGE layer: 64 rows/block, single-plane weights =====
// 8 B-loads + 8 MFMAs per s-iter (halved vs hi/lo). No LDS/barriers in main
// loop; B-frags = coalesced 1KB wave reads, L1/L2-hot (identical per block).
template <bool PROJ>
__global__ __launch_bounds__(256) void layer_mfma_kernel(
    const ushort* __restrict__ meanH, const ushort* __restrict__ rootH,
    const ushort* __restrict__ WTfrag, const float* __restrict__ bias,
    ushort* __restrict__ outH,
    const ushort* __restrict__ WoFrag, const float* __restrict__ bout,
    float* __restrict__ outF, int n) {
    __shared__ ushort sH[PROJ ? 64 : 1][136];    // stride 272B: 2-way max aliasing
    const int tid = threadIdx.x;
    const int w = tid >> 6;
    const int l = tid & 63;
    const int row0 = blockIdx.x * 64;
    const int lrow = w * 16 + (l & 15);
    const int kb = (l >> 4) * 8;
    const int lcol = l & 15;
    const int arowg = min(row0 + lrow, n - 1);

    const ushort* Am = meanH + (size_t)arowg * DD;
    const ushort* Ar = rootH + (size_t)arowg * DD;

    f32x4 acc[8];
    #pragma unroll
    for (int t = 0; t < 8; ++t) acc[t] = (f32x4){0.f, 0.f, 0.f, 0.f};

    #pragma unroll
    for (int s = 0; s < 8; ++s) {
        short8v ah = (s < 4) ? *(const short8v*)(Am + s * 32 + kb)
                             : *(const short8v*)(Ar + (s - 4) * 32 + kb);
        const ushort* fb = WTfrag + (size_t)s * 4096 + l * 8;
        #pragma unroll
        for (int t = 0; t < 8; ++t) {
            short8v bh = *(const short8v*)(fb + t * 512);
            acc[t] = __builtin_amdgcn_mfma_f32_16x16x32_bf16(ah, bh, acc[t], 0, 0, 0);
        }
    }

    // C/D layout: col = t*16 + (lane&15), row = w*16 + 4*(lane>>4) + reg
    const int lrow0 = w * 16 + (l >> 4) * 4;
    if (!PROJ) {
        #pragma unroll
        for (int t = 0; t < 8; ++t) {
            const int col = t * 16 + lcol;
            const float b = bias[col];
            #pragma unroll
            for (int r = 0; r < 4; ++r) {
                int row = row0 + lrow0 + r;
                if (row < n)
                    outH[(size_t)row * DD + col] = f2bf_rne(fmaxf(acc[t][r] + b, 0.f));
            }
        }
    } else {
        // wave-local transpose of h2 through sH (wave writes+reads only its rows)
        #pragma unroll
        for (int t = 0; t < 8; ++t) {
            const int col = t * 16 + lcol;
            const float b = bias[col];
            #pragma unroll
            for (int r = 0; r < 4; ++r) {
                sH[lrow0 + r][col] = f2bf_rne(fmaxf(acc[t][r] + b, 0.f));
            }
        }
        __syncthreads();
        f32x4 po[4];
        #pragma unroll
        for (int t = 0; t < 4; ++t) po[t] = (f32x4){0.f, 0.f, 0.f, 0.f};
        #pragma unroll
        for (int kc = 0; kc < 4; ++kc) {
            short8v ah = *(const short8v*)&sH[lrow][kc * 32 + kb];
            const ushort* fb = WoFrag + (size_t)kc * 2048 + l * 8;
            #pragma unroll
            for (int t = 0; t < 4; ++t) {
                short8v bh = *(const short8v*)(fb + t * 512);
                po[t] = __builtin_amdgcn_mfma_f32_16x16x32_bf16(ah, bh, po[t], 0, 0, 0);
            }
        }
        #pragma unroll
        for (int t = 0; t < 4; ++t) {
            const int col = t * 16 + lcol;
            const float b = bout[col];
            #pragma unroll
            for (int r = 0; r < 4; ++r) {
                int row = row0 + lrow0 + r;
                if (row < n) outF[(size_t)row * CC + col] = po[t][r] + b;
            }
        }
    }
}

extern "C" void kernel_launch(void* const* d_in, const int* in_sizes, int n_in,
                              void* d_out, int out_size, void* d_ws, size_t ws_size,
                              hipStream_t stream) {
    const float* x    = (const float*)d_in[0];
    const int*   ei   = (const int*)d_in[1];
    const float* W1l  = (const float*)d_in[2];
    const float* b1   = (const float*)d_in[3];
    const float* W1r  = (const float*)d_in[4];
    const float* W2l  = (const float*)d_in[5];
    const float* b2   = (const float*)d_in[6];
    const float* W2r  = (const float*)d_in[7];
    const float* Wout = (const float*)d_in[8];
    const float* bout = (const float*)d_in[9];
    float* out = (float*)d_out;
    const int n = in_sizes[0] / DD;       // 100000
    const int E = in_sizes[1] / 2;        // 1600000
    const size_t NP = (size_t)n * DD;

    const int NBUCK = (n + BKW - 1) / BKW;

    // workspace layout
    int* cnt   = (int*)d_ws;                              // 100352
    int* offs  = cnt + 100352;                            // 100352
    int* bcnt  = offs + 100352;                           // 256
    int* boffs = bcnt + 256;                              // 257 (pad 512)
    int* bcur  = boffs + 512;                             // 256
    int* csr   = bcur + 256;                              // E (pad)
    uint2* ebuf = (uint2*)(csr + 1600256);                // E pairs (12.8MB)
    ushort* xh  = (ushort*)ebuf;                          // union: n*128 bf16 (25.6MB)
    ushort* meanH = xh + NP;                              // n*128 bf16
    ushort* h1h = meanH + NP;                             // n*128 bf16
    ushort* WTfrag1 = h1h + NP;                           // 32768 ushorts each
    ushort* WTfrag2 = WTfrag1 + 32768;
    ushort* WoFrag  = WTfrag2 + 32768;                    // 8192 ushorts

    hipMemsetAsync(bcnt, 0, sizeof(int) * 256, stream);
    bucket_cnt_kernel<<<(E + 8191) / 8192, 256, 0, stream>>>(ei, bcnt, E);
    bucket_scan_kernel<<<1, 256, 0, stream>>>(bcnt, boffs, bcur);
    binA_kernel<<<(E + NPB - 1) / NPB, 256, 0, stream>>>(ei, bcur, ebuf, E);
    binB2_kernel<<<NBUCK, 256, 0, stream>>>(ebuf, boffs, offs, cnt, csr, n);

    dim3 wgrid(16, 2);
    wfrag_kernel<<<wgrid, 256, 0, stream>>>(W1l, W1r, W2l, W2r, WTfrag1, WTfrag2);
    wofrag_kernel<<<4, 256, 0, stream>>>(Wout, WoFrag);

    // ebuf dead now -> reuse region as xh
    xsplit_kernel<<<(n * DD / 8 + 255) / 256, 256, 0, stream>>>(x, xh, n * DD / 8);

    const int nblk = (n + 63) / 64;
    const int ablk = (n + 3) / 4;

    csr_agg4_kernel<<<ablk, 256, 0, stream>>>(xh, offs, cnt, csr, meanH, n);
    layer_mfma_kernel<false><<<nblk, 256, 0, stream>>>(
        meanH, xh, WTfrag1, b1, h1h,
        (const ushort*)nullptr, (const float*)nullptr, (float*)nullptr, n);

    csr_agg4_kernel<<<ablk, 256, 0, stream>>>(h1h, offs, cnt, csr, meanH, n);
    layer_mfma_kernel<true><<<nblk, 256, 0, stream>>>(
        meanH, h1h, WTfrag2, b2, (ushort*)nullptr,
        WoFrag, bout, out, n);
}

// Round 15
// 250.435 us; speedup vs baseline: 1.2129x; 1.0415x over previous
//
#include <hip/hip_runtime.h>

#define DD 128
#define CC 64
#define BKW 512            // nodes per bucket
#define NPB 4096           // edges per phase-B block

typedef __attribute__((ext_vector_type(8))) short short8v;
typedef __attribute__((ext_vector_type(4))) float f32x4;
typedef __attribute__((ext_vector_type(2))) float f32x2;

static __device__ inline ushort f2bf_rne(float f) {
    unsigned u = __float_as_uint(f);
    unsigned r = (u + 0x7FFFu + ((u >> 16) & 1u)) >> 16;
    return (ushort)r;
}
static __device__ inline float bf2f(ushort h) {
    return __uint_as_float(((unsigned)h) << 16);
}
static __device__ inline float bflo(uint u) {
    return __uint_as_float(u << 16);
}
static __device__ inline float bfhi(uint u) {
    return __uint_as_float(u & 0xffff0000u);
}

// ============ bucket histogram: per-block LDS hist, 256 global atomics ======
__global__ __launch_bounds__(256) void bucket_cnt_kernel(const int* __restrict__ ei,
                                                         int* __restrict__ bcnt, int E) {
    __shared__ int h[256];
    const int t = threadIdx.x;
    h[t] = 0;
    __syncthreads();
    const int base = blockIdx.x * 8192;
    const int end = min(E, base + 8192);
    for (int j = base + t; j < end; j += 256) {
        atomicAdd(&h[ei[E + j] >> 9], 1);
    }
    __syncthreads();
    if (h[t]) atomicAdd(&bcnt[t], h[t]);
}

// ============ bucket scan (256 entries, 1 block) -> boffs[257], bcur ========
__global__ __launch_bounds__(256) void bucket_scan_kernel(const int* __restrict__ bcnt,
                                                          int* __restrict__ boffs,
                                                          int* __restrict__ bcur) {
    __shared__ int s[256];
    const int t = threadIdx.x;
    int v = bcnt[t];
    s[t] = v;
    __syncthreads();
    for (int off = 1; off < 256; off <<= 1) {
        int xv = 0;
        if (t >= off) xv = s[t - off];
        __syncthreads();
        if (t >= off) s[t] += xv;
        __syncthreads();
    }
    int excl = s[t] - v;
    boffs[t] = excl;
    bcur[t] = excl;
    if (t == 255) boffs[256] = s[255];
}

// ===== phase B: bin edges by bucket; packed word = src | (dst&511)<<17 ======
// bucket id (0..195, needs 8 bits) carried in a separate byte array — it does
// NOT fit above bit 26 of the packed word (R14 bug).
__global__ __launch_bounds__(256) void binA_kernel(const int* __restrict__ ei,
                                                   int* __restrict__ bcur,
                                                   uint* __restrict__ ebuf, int E) {
    __shared__ int sRun[256];
    __shared__ int sRel[256];
    __shared__ int sBase[256];
    __shared__ uint sPair[NPB];
    __shared__ unsigned char sBkt[NPB];
    __shared__ int sHist[256];
    const int t = threadIdx.x;
    const int e0 = blockIdx.x * NPB;
    const int cntE = min(NPB, E - e0);

    sHist[t] = 0;
    __syncthreads();
    for (int j = t; j < cntE; j += 256) {
        int dst = ei[E + e0 + j];
        atomicAdd(&sHist[dst >> 9], 1);
    }
    __syncthreads();
    int h = sHist[t];
    sRun[t] = h;
    __syncthreads();
    for (int off = 1; off < 256; off <<= 1) {
        int v = 0;
        if (t >= off) v = sRun[t - off];
        __syncthreads();
        if (t >= off) sRun[t] += v;
        __syncthreads();
    }
    int runstart = sRun[t] - h;
    int base = 0;
    if (h > 0) base = atomicAdd(&bcur[t], h);
    sRun[t] = runstart;
    sRel[t] = runstart;
    sBase[t] = base;
    __syncthreads();
    // stage packed (src, dloc) bucket-sorted in LDS; bucket id in sBkt
    for (int j = t; j < cntE; j += 256) {
        int src = ei[e0 + j];
        int dst = ei[E + e0 + j];
        int b = dst >> 9;
        int slot = atomicAdd(&sRel[b], 1);
        sPair[slot] = (uint)src | ((uint)(dst & 511) << 17);
        sBkt[slot] = (unsigned char)b;
    }
    __syncthreads();
    for (int s = t; s < cntE; s += 256) {
        uint p = sPair[s];
        int b = (int)sBkt[s];
        int gpos = sBase[b] + (s - sRun[b]);
        ebuf[gpos] = p;
    }
}

// ====== phase C: per-bucket: derive per-node cnt/offs in LDS, then scatter ====
__global__ __launch_bounds__(256) void binB2_kernel(const uint* __restrict__ ebuf,
                                                    const int* __restrict__ boffs,
                                                    int* __restrict__ offs,
                                                    int* __restrict__ cnt,
                                                    int* __restrict__ csr, int n) {
    __shared__ int sCnt[BKW];
    __shared__ int sOffs[BKW];
    __shared__ int sScan[256];
    const int t = threadIdx.x;
    const int node0 = blockIdx.x * BKW;
    const int start = boffs[blockIdx.x];
    const int end = boffs[blockIdx.x + 1];

    sCnt[t] = 0; sCnt[t + 256] = 0;
    __syncthreads();
    for (int j = start + t; j < end; j += 256) {
        int d = (int)(ebuf[j] >> 17);
        atomicAdd(&sCnt[d], 1);
    }
    __syncthreads();
    int v0 = sCnt[2 * t], v1 = sCnt[2 * t + 1];
    int sum = v0 + v1;
    sScan[t] = sum;
    __syncthreads();
    for (int off = 1; off < 256; off <<= 1) {
        int xv = 0;
        if (t >= off) xv = sScan[t - off];
        __syncthreads();
        if (t >= off) sScan[t] += xv;
        __syncthreads();
    }
    int excl = sScan[t] - sum;
    sOffs[2 * t] = start + excl;
    sOffs[2 * t + 1] = start + excl + v0;
    __syncthreads();
    for (int i = t; i < BKW; i += 256) {
        int node = node0 + i;
        if (node < n) { offs[node] = sOffs[i]; cnt[node] = sCnt[i]; }
    }
    __syncthreads();
    sCnt[t] = 0; sCnt[t + 256] = 0;
    __syncthreads();
    for (int j = start + t; j < end; j += 256) {
        uint p = ebuf[j];
        int d = (int)(p >> 17);
        int r = atomicAdd(&sCnt[d], 1);
        csr[sOffs[d] + r] = (int)(p & 0x1FFFFu);
    }
}

// ================= f32 -> bf16 hi plane =================
__global__ __launch_bounds__(256) void xsplit_kernel(const float* __restrict__ x,
                                                     ushort* __restrict__ xh,
                                                     int total8) {
    int i = blockIdx.x * 256 + threadIdx.x;
    if (i >= total8) return;
    float4 a = ((const float4*)x)[2 * i];
    float4 b = ((const float4*)x)[2 * i + 1];
    ushort r[8] = {f2bf_rne(a.x), f2bf_rne(a.y), f2bf_rne(a.z), f2bf_rne(a.w),
                   f2bf_rne(b.x), f2bf_rne(b.y), f2bf_rne(b.z), f2bf_rne(b.w)};
    uint4 o;
    o.x = (uint)r[0] | ((uint)r[1] << 16);
    o.y = (uint)r[2] | ((uint)r[3] << 16);
    o.z = (uint)r[4] | ((uint)r[5] << 16);
    o.w = (uint)r[6] | ((uint)r[7] << 16);
    ((uint4*)xh)[i] = o;
}

// ====== CSR gather-aggregate: up to 16 neighbors in flight, f32x2 accum =====
__global__ __launch_bounds__(256) void csr_agg4_kernel(
    const ushort* __restrict__ xh, const int* __restrict__ offs,
    const int* __restrict__ cnt, const int* __restrict__ csr,
    ushort* __restrict__ meanH, int n) {
    int node = blockIdx.x * 4 + (threadIdx.x >> 6);
    if (node >= n) return;
    const int lane = threadIdx.x & 63;
    const int sub = lane >> 4;
    const int li = lane & 15;
    const int start = offs[node];
    const int c = cnt[node];
    f32x2 a[4], aa[4];
    #pragma unroll
    for (int k = 0; k < 4; ++k) { a[k] = (f32x2){0.f, 0.f}; aa[k] = (f32x2){0.f, 0.f}; }
    #define ACC4(A, U) \
        A[0] += (f32x2){bflo(U.x), bfhi(U.x)}; \
        A[1] += (f32x2){bflo(U.y), bfhi(U.y)}; \
        A[2] += (f32x2){bflo(U.z), bfhi(U.z)}; \
        A[3] += (f32x2){bflo(U.w), bfhi(U.w)};
    const int c16 = c & ~15;
    int j = 0;
    if (c16 > 0) {
        int s0 = csr[start + sub];
        int s1 = csr[start + 4 + sub];
        int s2 = csr[start + 8 + sub];
        int s3 = csr[start + 12 + sub];
        for (; j < c16; j += 16) {
            int t0 = 0, t1 = 0, t2 = 0, t3 = 0;
            if (j + 16 < c16) {
                t0 = csr[start + j + 16 + sub];
                t1 = csr[start + j + 20 + sub];
                t2 = csr[start + j + 24 + sub];
                t3 = csr[start + j + 28 + sub];
            }
            uint4 u0 = *(const uint4*)(xh + (size_t)s0 * DD + li * 8);
            uint4 u1 = *(const uint4*)(xh + (size_t)s1 * DD + li * 8);
            uint4 u2 = *(const uint4*)(xh + (size_t)s2 * DD + li * 8);
            uint4 u3 = *(const uint4*)(xh + (size_t)s3 * DD + li * 8);
            ACC4(a, u0); ACC4(a, u1); ACC4(aa, u2); ACC4(aa, u3);
            s0 = t0; s1 = t1; s2 = t2; s3 = t3;
        }
    }
    if (c - j >= 8) {
        int s0 = csr[start + j + sub];
        int s1 = csr[start + j + 4 + sub];
        uint4 u0 = *(const uint4*)(xh + (size_t)s0 * DD + li * 8);
        uint4 u1 = *(const uint4*)(xh + (size_t)s1 * DD + li * 8);
        ACC4(a, u0); ACC4(aa, u1);
        j += 8;
    }
    if (c - j >= 4) {
        int s = csr[start + j + sub];
        uint4 u = *(const uint4*)(xh + (size_t)s * DD + li * 8);
        ACC4(a, u);
        j += 4;
    }
    if (j + sub < c) {
        int s = csr[start + j + sub];
        uint4 u = *(const uint4*)(xh + (size_t)s * DD + li * 8);
        ACC4(aa, u);
    }
    #undef ACC4
    float res[8];
    #pragma unroll
    for (int k = 0; k < 4; ++k) {
        f32x2 v = a[k] + aa[k];
        float e0 = v.x; e0 += __shfl_xor(e0, 16); e0 += __shfl_xor(e0, 32);
        float e1 = v.y; e1 += __shfl_xor(e1, 16); e1 += __shfl_xor(e1, 32);
        res[2 * k] = e0; res[2 * k + 1] = e1;
    }
    if (sub == 0) {
        float inv = 1.0f / fmaxf((float)c, 1.0f);
        short8v o;
        #pragma unroll
        for (int k = 0; k < 8; ++k) o[k] = (short)f2bf_rne(res[k] * inv);
        *(short8v*)(meanH + (size_t)node * DD + li * 8) = o;
    }
}

// ====== weight prep: single-plane bf16 MFMA-frag layout ======
__global__ __launch_bounds__(256) void wfrag_kernel(
    const float* __restrict__ Wl1, const float* __restrict__ Wr1,
    const float* __restrict__ Wl2, const float* __restrict__ Wr2,
    ushort* __restrict__ WTfrag1, ushort* __restrict__ WTfrag2) {
    int idx = blockIdx.x * 256 + threadIdx.x;     // [0, 4096)
    if (idx >= 4096) return;
    const float* Wl = blockIdx.y ? Wl2 : Wl1;
    const float* Wr = blockIdx.y ? Wr2 : Wr1;
    ushort* dst = (blockIdx.y ? WTfrag2 : WTfrag1) + (size_t)idx * 8;
    int lane = idx & 63, t = (idx >> 6) & 7, s = idx >> 9;
    int col = t * 16 + (lane & 15);
    int k0 = s * 32 + (lane >> 4) * 8;
    #pragma unroll
    for (int j = 0; j < 8; ++j) {
        int k = k0 + j;
        float v = (k < DD) ? Wl[k * DD + col] : Wr[(k - DD) * DD + col];
        dst[j] = f2bf_rne(v);
    }
}

__global__ __launch_bounds__(256) void wofrag_kernel(const float* __restrict__ Wout,
                                                     ushort* __restrict__ WoFrag) {
    int idx = blockIdx.x * 256 + threadIdx.x;     // [0, 1024)
    if (idx >= 1024) return;
    ushort* dst = WoFrag + (size_t)idx * 8;
    int lane = idx & 63, t = (idx >> 6) & 3, kc = idx >> 8;
    int col = t * 16 + (lane & 15);
    int k0 = kc * 32 + (lane >> 4) * 8;
    #pragma unroll
    for (int j = 0; j < 8; ++j) {
        dst[j] = f2bf_rne(Wout[(k0 + j) * CC + col]);
    }
}

// ===== MFMA SAGE layer: 512 thr / 128 rows / WTfrag in LDS / A prefetched ====
// Stage the whole 64KB single-plane WTfrag to LDS once (contiguous b128 reads,
// shared by 8 waves); prefetch all 8 A-frags per lane before the barrier.
// K-loop: pure ds_read_b128 + MFMA, no barriers. PROJ reuses LDS for h2.
template <bool PROJ>
__global__ __launch_bounds__(512) void layer_mfma_kernel(
    const ushort* __restrict__ meanH, const ushort* __restrict__ rootH,
    const ushort* __restrict__ WTfrag, const float* __restrict__ bias,
    ushort* __restrict__ outH,
    const ushort* __restrict__ WoFrag, const float* __restrict__ bout,
    float* __restrict__ outF, int n) {
    __shared__ ushort sB[32768];                 // 64 KB
    const int tid = threadIdx.x;
    const int w = tid >> 6;                      // wave 0..7
    const int l = tid & 63;
    const int row0 = blockIdx.x * 128;
    const int lrow = w * 16 + (l & 15);          // this lane's A row (in-block)
    const int kb = (l >> 4) * 8;
    const int lcol = l & 15;
    const int arowg = min(row0 + lrow, n - 1);

    const ushort* Am = meanH + (size_t)arowg * DD;
    const ushort* Ar = rootH + (size_t)arowg * DD;

    // prefetch all 8 A-frags (independent 16B loads)
    short8v ap[8];
    #pragma unroll
    for (int s = 0; s < 8; ++s) {
        ap[s] = (s < 4) ? *(const short8v*)(Am + s * 32 + kb)
                        : *(const short8v*)(Ar + (s - 4) * 32 + kb);
    }
    // stage WTfrag -> LDS (4096 x 16B, linear)
    for (int i = tid; i < 4096; i += 512) {
        ((short8v*)sB)[i] = ((const short8v*)WTfrag)[i];
    }
    __syncthreads();

    f32x4 acc[8];
    #pragma unroll
    for (int t = 0; t < 8; ++t) acc[t] = (f32x4){0.f, 0.f, 0.f, 0.f};

    #pragma unroll
    for (int s = 0; s < 8; ++s) {
        #pragma unroll
        for (int t = 0; t < 8; ++t) {
            short8v bh = *(const short8v*)&sB[s * 4096 + t * 512 + l * 8];
            acc[t] = __builtin_amdgcn_mfma_f32_16x16x32_bf16(ap[s], bh, acc[t], 0, 0, 0);
        }
    }

    // C/D layout: col = t*16 + (lane&15), row = w*16 + 4*(lane>>4) + reg
    const int lrow0 = w * 16 + (l >> 4) * 4;
    if (!PROJ) {
        #pragma unroll
        for (int t = 0; t < 8; ++t) {
            const int col = t * 16 + lcol;
            const float b = bias[col];
            #pragma unroll
            for (int r = 0; r < 4; ++r) {
                int row = row0 + lrow0 + r;
                if (row < n)
                    outH[(size_t)row * DD + col] = f2bf_rne(fmaxf(acc[t][r] + b, 0.f));
            }
        }
    } else {
        // all waves done reading sB -> reuse as sH[128][136]
        __syncthreads();
        ushort (*sH)[136] = (ushort(*)[136])sB;
        #pragma unroll
        for (int t = 0; t < 8; ++t) {
            const int col = t * 16 + lcol;
            const float b = bias[col];
            #pragma unroll
            for (int r = 0; r < 4; ++r) {
                sH[lrow0 + r][col] = f2bf_rne(fmaxf(acc[t][r] + b, 0.f));
            }
        }
        // wave-local: each wave reads only rows it wrote (in-wave LDS ordering)
        f32x4 po[4];
        #pragma unroll
        for (int t = 0; t < 4; ++t) po[t] = (f32x4){0.f, 0.f, 0.f, 0.f};
        #pragma unroll
        for (int kc = 0; kc < 4; ++kc) {
            short8v ah = *(const short8v*)&sH[lrow][kc * 32 + kb];
            const ushort* fb = WoFrag + (size_t)kc * 2048 + l * 8;
            #pragma unroll
            for (int t = 0; t < 4; ++t) {
                short8v bh = *(const short8v*)(fb + t * 512);
                po[t] = __builtin_amdgcn_mfma_f32_16x16x32_bf16(ah, bh, po[t], 0, 0, 0);
            }
        }
        #pragma unroll
        for (int t = 0; t < 4; ++t) {
            const int col = t * 16 + lcol;
            const float b = bout[col];
            #pragma unroll
            for (int r = 0; r < 4; ++r) {
                int row = row0 + lrow0 + r;
                if (row < n) outF[(size_t)row * CC + col] = po[t][r] + b;
            }
        }
    }
}

extern "C" void kernel_launch(void* const* d_in, const int* in_sizes, int n_in,
                              void* d_out, int out_size, void* d_ws, size_t ws_size,
                              hipStream_t stream) {
    const float* x    = (const float*)d_in[0];
    const int*   ei   = (const int*)d_in[1];
    const float* W1l  = (const float*)d_in[2];
    const float* b1   = (const float*)d_in[3];
    const float* W1r  = (const float*)d_in[4];
    const float* W2l  = (const float*)d_in[5];
    const float* b2   = (const float*)d_in[6];
    const float* W2r  = (const float*)d_in[7];
    const float* Wout = (const float*)d_in[8];
    const float* bout = (const float*)d_in[9];
    float* out = (float*)d_out;
    const int n = in_sizes[0] / DD;       // 100000
    const int E = in_sizes[1] / 2;        // 1600000
    const size_t NP = (size_t)n * DD;

    const int NBUCK = (n + BKW - 1) / BKW;

    // workspace layout
    int* cnt   = (int*)d_ws;                              // 100352
    int* offs  = cnt + 100352;                            // 100352
    int* bcnt  = offs + 100352;                           // 256
    int* boffs = bcnt + 256;                              // 257 (pad 512)
    int* bcur  = boffs + 512;                             // 256
    int* csr   = bcur + 256;                              // E (pad)
    uint* ebuf = (uint*)(csr + 1600256);                  // E packed words (6.4MB)
    ushort* xh  = (ushort*)ebuf;                          // union: n*128 bf16 (25.6MB)
    ushort* meanH = xh + NP;                              // n*128 bf16
    ushort* h1h = meanH + NP;                             // n*128 bf16
    ushort* WTfrag1 = h1h + NP;                           // 32768 ushorts each
    ushort* WTfrag2 = WTfrag1 + 32768;
    ushort* WoFrag  = WTfrag2 + 32768;                    // 8192 ushorts

    hipMemsetAsync(bcnt, 0, sizeof(int) * 256, stream);
    bucket_cnt_kernel<<<(E + 8191) / 8192, 256, 0, stream>>>(ei, bcnt, E);
    bucket_scan_kernel<<<1, 256, 0, stream>>>(bcnt, boffs, bcur);
    binA_kernel<<<(E + NPB - 1) / NPB, 256, 0, stream>>>(ei, bcur, ebuf, E);
    binB2_kernel<<<NBUCK, 256, 0, stream>>>(ebuf, boffs, offs, cnt, csr, n);

    dim3 wgrid(16, 2);
    wfrag_kernel<<<wgrid, 256, 0, stream>>>(W1l, W1r, W2l, W2r, WTfrag1, WTfrag2);
    wofrag_kernel<<<4, 256, 0, stream>>>(Wout, WoFrag);

    // ebuf dead now -> reuse region as xh
    xsplit_kernel<<<(n * DD / 8 + 255) / 256, 256, 0, stream>>>(x, xh, n * DD / 8);

    const int nblk = (n + 127) / 128;
    const int ablk = (n + 3) / 4;

    csr_agg4_kernel<<<ablk, 256, 0, stream>>>(xh, offs, cnt, csr, meanH, n);
    layer_mfma_kernel<false><<<nblk, 512, 0, stream>>>(
        meanH, xh, WTfrag1, b1, h1h,
        (const ushort*)nullptr, (const float*)nullptr, (float*)nullptr, n);

    csr_agg4_kernel<<<ablk, 256, 0, stream>>>(h1h, offs, cnt, csr, meanH, n);
    layer_mfma_kernel<true><<<nblk, 512, 0, stream>>>(
        meanH, h1h, WTfrag2, b2, (ushort*)nullptr,
        WoFrag, bout, out, n);
}

// Round 16
// 233.681 us; speedup vs baseline: 1.2998x; 1.0717x over previous
//
#include <hip/hip_runtime.h>
#include <hip/hip_fp8.h>

#define DD 128
#define CC 64
#define BKW 512            // nodes per bucket
#define NPB 4096           // edges per phase-B block

typedef __attribute__((ext_vector_type(8))) short short8v;
typedef __attribute__((ext_vector_type(4))) float f32x4;
typedef __attribute__((ext_vector_type(2))) float f32x2;

static __device__ inline ushort f2bf_rne(float f) {
    unsigned u = __float_as_uint(f);
    unsigned r = (u + 0x7FFFu + ((u >> 16) & 1u)) >> 16;
    return (ushort)r;
}
static __device__ inline float bf2f(ushort h) {
    return __uint_as_float(((unsigned)h) << 16);
}
static __device__ inline float bflo(uint u) {
    return __uint_as_float(u << 16);
}
static __device__ inline float bfhi(uint u) {
    return __uint_as_float(u & 0xffff0000u);
}

// ============ bucket histogram: per-block LDS hist, 256 global atomics ======
__global__ __launch_bounds__(256) void bucket_cnt_kernel(const int* __restrict__ ei,
                                                         int* __restrict__ bcnt, int E) {
    __shared__ int h[256];
    const int t = threadIdx.x;
    h[t] = 0;
    __syncthreads();
    const int base = blockIdx.x * 8192;
    const int end = min(E, base + 8192);
    for (int j = base + t; j < end; j += 256) {
        atomicAdd(&h[ei[E + j] >> 9], 1);
    }
    __syncthreads();
    if (h[t]) atomicAdd(&bcnt[t], h[t]);
}

// ============ bucket scan (256 entries, 1 block) -> boffs[257], bcur ========
__global__ __launch_bounds__(256) void bucket_scan_kernel(const int* __restrict__ bcnt,
                                                          int* __restrict__ boffs,
                                                          int* __restrict__ bcur) {
    __shared__ int s[256];
    const int t = threadIdx.x;
    int v = bcnt[t];
    s[t] = v;
    __syncthreads();
    for (int off = 1; off < 256; off <<= 1) {
        int xv = 0;
        if (t >= off) xv = s[t - off];
        __syncthreads();
        if (t >= off) s[t] += xv;
        __syncthreads();
    }
    int excl = s[t] - v;
    boffs[t] = excl;
    bcur[t] = excl;
    if (t == 255) boffs[256] = s[255];
}

// ===== phase B: bin edges by bucket; packed word = src | (dst&511)<<17 ======
// bucket id (0..195, 8 bits) in a separate byte array (R14 lesson).
__global__ __launch_bounds__(256) void binA_kernel(const int* __restrict__ ei,
                                                   int* __restrict__ bcur,
                                                   uint* __restrict__ ebuf, int E) {
    __shared__ int sRun[256];
    __shared__ int sRel[256];
    __shared__ int sBase[256];
    __shared__ uint sPair[NPB];
    __shared__ unsigned char sBkt[NPB];
    __shared__ int sHist[256];
    const int t = threadIdx.x;
    const int e0 = blockIdx.x * NPB;
    const int cntE = min(NPB, E - e0);

    sHist[t] = 0;
    __syncthreads();
    for (int j = t; j < cntE; j += 256) {
        int dst = ei[E + e0 + j];
        atomicAdd(&sHist[dst >> 9], 1);
    }
    __syncthreads();
    int h = sHist[t];
    sRun[t] = h;
    __syncthreads();
    for (int off = 1; off < 256; off <<= 1) {
        int v = 0;
        if (t >= off) v = sRun[t - off];
        __syncthreads();
        if (t >= off) sRun[t] += v;
        __syncthreads();
    }
    int runstart = sRun[t] - h;
    int base = 0;
    if (h > 0) base = atomicAdd(&bcur[t], h);
    sRun[t] = runstart;
    sRel[t] = runstart;
    sBase[t] = base;
    __syncthreads();
    for (int j = t; j < cntE; j += 256) {
        int src = ei[e0 + j];
        int dst = ei[E + e0 + j];
        int b = dst >> 9;
        int slot = atomicAdd(&sRel[b], 1);
        sPair[slot] = (uint)src | ((uint)(dst & 511) << 17);
        sBkt[slot] = (unsigned char)b;
    }
    __syncthreads();
    for (int s = t; s < cntE; s += 256) {
        uint p = sPair[s];
        int b = (int)sBkt[s];
        int gpos = sBase[b] + (s - sRun[b]);
        ebuf[gpos] = p;
    }
}

// ====== phase C: per-bucket: derive per-node offs in LDS, then scatter =====
// cnt array eliminated: cnt[i] == offs[i+1]-offs[i]; last block writes offs[n]=E.
__global__ __launch_bounds__(256) void binB2_kernel(const uint* __restrict__ ebuf,
                                                    const int* __restrict__ boffs,
                                                    int* __restrict__ offs,
                                                    int* __restrict__ csr, int n) {
    __shared__ int sCnt[BKW];
    __shared__ int sOffs[BKW];
    __shared__ int sScan[256];
    const int t = threadIdx.x;
    const int node0 = blockIdx.x * BKW;
    const int node1 = min(n, node0 + BKW);
    const int start = boffs[blockIdx.x];
    const int end = boffs[blockIdx.x + 1];

    sCnt[t] = 0; sCnt[t + 256] = 0;
    __syncthreads();
    for (int j = start + t; j < end; j += 256) {
        int d = (int)(ebuf[j] >> 17);
        atomicAdd(&sCnt[d], 1);
    }
    __syncthreads();
    int v0 = sCnt[2 * t], v1 = sCnt[2 * t + 1];
    int sum = v0 + v1;
    sScan[t] = sum;
    __syncthreads();
    for (int off = 1; off < 256; off <<= 1) {
        int xv = 0;
        if (t >= off) xv = sScan[t - off];
        __syncthreads();
        if (t >= off) sScan[t] += xv;
        __syncthreads();
    }
    int excl = sScan[t] - sum;
    sOffs[2 * t] = start + excl;
    sOffs[2 * t + 1] = start + excl + v0;
    __syncthreads();
    for (int i = t; i < BKW; i += 256) {
        int node = node0 + i;
        if (node < n) offs[node] = sOffs[i];
    }
    if (node1 == n && t == 0) offs[n] = end;
    __syncthreads();
    sCnt[t] = 0; sCnt[t + 256] = 0;
    __syncthreads();
    for (int j = start + t; j < end; j += 256) {
        uint p = ebuf[j];
        int d = (int)(p >> 17);
        int r = atomicAdd(&sCnt[d], 1);
        csr[sOffs[d] + r] = (int)(p & 0x1FFFFu);
    }
}

// ===== merged prep: x -> (xh bf16, xq e4m3) + wfrag + wofrag ===============
__global__ __launch_bounds__(256) void prep_kernel(
    const float* __restrict__ x, ushort* __restrict__ xh, uint* __restrict__ xq,
    const float* __restrict__ Wl1, const float* __restrict__ Wr1,
    const float* __restrict__ Wl2, const float* __restrict__ Wr2,
    const float* __restrict__ Wout,
    ushort* __restrict__ WTfrag1, ushort* __restrict__ WTfrag2,
    ushort* __restrict__ WoFrag, int nxblk) {
    const int t = threadIdx.x;
    const int bx = blockIdx.x;
    if (bx < nxblk) {
        int i = bx * 256 + t;                    // 8 elems per thread
        float4 a = ((const float4*)x)[2 * i];
        float4 b = ((const float4*)x)[2 * i + 1];
        float vv[8] = {a.x, a.y, a.z, a.w, b.x, b.y, b.z, b.w};
        ushort r[8];
        uint q[8];
        #pragma unroll
        for (int j = 0; j < 8; ++j) {
            r[j] = f2bf_rne(vv[j]);
            q[j] = (uint)__hip_fp8_e4m3(vv[j]).__x;
        }
        uint4 o;
        o.x = (uint)r[0] | ((uint)r[1] << 16);
        o.y = (uint)r[2] | ((uint)r[3] << 16);
        o.z = (uint)r[4] | ((uint)r[5] << 16);
        o.w = (uint)r[6] | ((uint)r[7] << 16);
        ((uint4*)xh)[i] = o;
        uint2 oq;
        oq.x = q[0] | (q[1] << 8) | (q[2] << 16) | (q[3] << 24);
        oq.y = q[4] | (q[5] << 8) | (q[6] << 16) | (q[7] << 24);
        ((uint2*)xq)[i] = oq;
    } else if (bx < nxblk + 32) {
        int li = bx - nxblk;
        int layer = li >> 4;
        int idx = (li & 15) * 256 + t;           // [0, 4096)
        const float* Wl = layer ? Wl2 : Wl1;
        const float* Wr = layer ? Wr2 : Wr1;
        ushort* dst = (layer ? WTfrag2 : WTfrag1) + (size_t)idx * 8;
        int lane = idx & 63, tt = (idx >> 6) & 7, s = idx >> 9;
        int col = tt * 16 + (lane & 15);
        int k0 = s * 32 + (lane >> 4) * 8;
        #pragma unroll
        for (int j = 0; j < 8; ++j) {
            int k = k0 + j;
            float v = (k < DD) ? Wl[k * DD + col] : Wr[(k - DD) * DD + col];
            dst[j] = f2bf_rne(v);
        }
    } else {
        int idx = (bx - nxblk - 32) * 256 + t;   // [0, 1024)
        ushort* dst = WoFrag + (size_t)idx * 8;
        int lane = idx & 63, tt = (idx >> 6) & 3, kc = idx >> 8;
        int col = tt * 16 + (lane & 15);
        int k0 = kc * 32 + (lane >> 4) * 8;
        #pragma unroll
        for (int j = 0; j < 8; ++j) {
            dst[j] = f2bf_rne(Wout[(k0 + j) * CC + col]);
        }
    }
}

// ====== CSR gather-aggregate, fp8 rows (layer-1 only): 16 nbrs in flight ====
__global__ __launch_bounds__(256) void csr_agg8_kernel(
    const uint* __restrict__ xq, const int* __restrict__ offs,
    const int* __restrict__ csr, ushort* __restrict__ meanH, int n) {
    int node = blockIdx.x * 4 + (threadIdx.x >> 6);
    if (node >= n) return;
    const int lane = threadIdx.x & 63;
    const int sub = lane >> 4;
    const int li = lane & 15;
    const int start = offs[node];
    const int c = offs[node + 1] - start;
    f32x2 a[4], aa[4];
    #pragma unroll
    for (int k = 0; k < 4; ++k) { a[k] = (f32x2){0.f, 0.f}; aa[k] = (f32x2){0.f, 0.f}; }
    // row = 128 fp8 bytes; lane loads uint2 (8 dims)
    #define ACC8(A, U) { \
        A[0] += __builtin_amdgcn_cvt_pk_f32_fp8(U.x, false); \
        A[1] += __builtin_amdgcn_cvt_pk_f32_fp8(U.x, true);  \
        A[2] += __builtin_amdgcn_cvt_pk_f32_fp8(U.y, false); \
        A[3] += __builtin_amdgcn_cvt_pk_f32_fp8(U.y, true);  }
    const int c16 = c & ~15;
    int j = 0;
    if (c16 > 0) {
        int s0 = csr[start + sub];
        int s1 = csr[start + 4 + sub];
        int s2 = csr[start + 8 + sub];
        int s3 = csr[start + 12 + sub];
        for (; j < c16; j += 16) {
            int t0 = 0, t1 = 0, t2 = 0, t3 = 0;
            if (j + 16 < c16) {
                t0 = csr[start + j + 16 + sub];
                t1 = csr[start + j + 20 + sub];
                t2 = csr[start + j + 24 + sub];
                t3 = csr[start + j + 28 + sub];
            }
            uint2 u0 = *(const uint2*)((const uchar*)xq + (size_t)s0 * DD + li * 8);
            uint2 u1 = *(const uint2*)((const uchar*)xq + (size_t)s1 * DD + li * 8);
            uint2 u2 = *(const uint2*)((const uchar*)xq + (size_t)s2 * DD + li * 8);
            uint2 u3 = *(const uint2*)((const uchar*)xq + (size_t)s3 * DD + li * 8);
            ACC8(a, u0); ACC8(a, u1); ACC8(aa, u2); ACC8(aa, u3);
            s0 = t0; s1 = t1; s2 = t2; s3 = t3;
        }
    }
    if (c - j >= 8) {
        int s0 = csr[start + j + sub];
        int s1 = csr[start + j + 4 + sub];
        uint2 u0 = *(const uint2*)((const uchar*)xq + (size_t)s0 * DD + li * 8);
        uint2 u1 = *(const uint2*)((const uchar*)xq + (size_t)s1 * DD + li * 8);
        ACC8(a, u0); ACC8(aa, u1);
        j += 8;
    }
    if (c - j >= 4) {
        int s = csr[start + j + sub];
        uint2 u = *(const uint2*)((const uchar*)xq + (size_t)s * DD + li * 8);
        ACC8(a, u);
        j += 4;
    }
    if (j + sub < c) {
        int s = csr[start + j + sub];
        uint2 u = *(const uint2*)((const uchar*)xq + (size_t)s * DD + li * 8);
        ACC8(aa, u);
    }
    #undef ACC8
    float res[8];
    #pragma unroll
    for (int k = 0; k < 4; ++k) {
        f32x2 v = a[k] + aa[k];
        float e0 = v.x; e0 += __shfl_xor(e0, 16); e0 += __shfl_xor(e0, 32);
        float e1 = v.y; e1 += __shfl_xor(e1, 16); e1 += __shfl_xor(e1, 32);
        res[2 * k] = e0; res[2 * k + 1] = e1;
    }
    if (sub == 0) {
        float inv = 1.0f / fmaxf((float)c, 1.0f);
        short8v o;
        #pragma unroll
        for (int k = 0; k < 8; ++k) o[k] = (short)f2bf_rne(res[k] * inv);
        *(short8v*)(meanH + (size_t)node * DD + li * 8) = o;
    }
}

// ====== CSR gather-aggregate, bf16 rows (layer-2): 16 nbrs in flight ========
__global__ __launch_bounds__(256) void csr_agg4_kernel(
    const ushort* __restrict__ xh, const int* __restrict__ offs,
    const int* __restrict__ csr, ushort* __restrict__ meanH, int n) {
    int node = blockIdx.x * 4 + (threadIdx.x >> 6);
    if (node >= n) return;
    const int lane = threadIdx.x & 63;
    const int sub = lane >> 4;
    const int li = lane & 15;
    const int start = offs[node];
    const int c = offs[node + 1] - start;
    f32x2 a[4], aa[4];
    #pragma unroll
    for (int k = 0; k < 4; ++k) { a[k] = (f32x2){0.f, 0.f}; aa[k] = (f32x2){0.f, 0.f}; }
    #define ACC4(A, U) \
        A[0] += (f32x2){bflo(U.x), bfhi(U.x)}; \
        A[1] += (f32x2){bflo(U.y), bfhi(U.y)}; \
        A[2] += (f32x2){bflo(U.z), bfhi(U.z)}; \
        A[3] += (f32x2){bflo(U.w), bfhi(U.w)};
    const int c16 = c & ~15;
    int j = 0;
    if (c16 > 0) {
        int s0 = csr[start + sub];
        int s1 = csr[start + 4 + sub];
        int s2 = csr[start + 8 + sub];
        int s3 = csr[start + 12 + sub];
        for (; j < c16; j += 16) {
            int t0 = 0, t1 = 0, t2 = 0, t3 = 0;
            if (j + 16 < c16) {
                t0 = csr[start + j + 16 + sub];
                t1 = csr[start + j + 20 + sub];
                t2 = csr[start + j + 24 + sub];
                t3 = csr[start + j + 28 + sub];
            }
            uint4 u0 = *(const uint4*)(xh + (size_t)s0 * DD + li * 8);
            uint4 u1 = *(const uint4*)(xh + (size_t)s1 * DD + li * 8);
            uint4 u2 = *(const uint4*)(xh + (size_t)s2 * DD + li * 8);
            uint4 u3 = *(const uint4*)(xh + (size_t)s3 * DD + li * 8);
            ACC4(a, u0); ACC4(a, u1); ACC4(aa, u2); ACC4(aa, u3);
            s0 = t0; s1 = t1; s2 = t2; s3 = t3;
        }
    }
    if (c - j >= 8) {
        int s0 = csr[start + j + sub];
        int s1 = csr[start + j + 4 + sub];
        uint4 u0 = *(const uint4*)(xh + (size_t)s0 * DD + li * 8);
        uint4 u1 = *(const uint4*)(xh + (size_t)s1 * DD + li * 8);
        ACC4(a, u0); ACC4(aa, u1);
        j += 8;
    }
    if (c - j >= 4) {
        int s = csr[start + j + sub];
        uint4 u = *(const uint4*)(xh + (size_t)s * DD + li * 8);
        ACC4(a, u);
        j += 4;
    }
    if (j + sub < c) {
        int s = csr[start + j + sub];
        uint4 u = *(const uint4*)(xh + (size_t)s * DD + li * 8);
        ACC4(aa, u);
    }
    #undef ACC4
    float res[8];
    #pragma unroll
    for (int k = 0; k < 4; ++k) {
        f32x2 v = a[k] + aa[k];
        float e0 = v.x; e0 += __shfl_xor(e0, 16); e0 += __shfl_xor(e0, 32);
        float e1 = v.y; e1 += __shfl_xor(e1, 16); e1 += __shfl_xor(e1, 32);
        res[2 * k] = e0; res[2 * k + 1] = e1;
    }
    if (sub == 0) {
        float inv = 1.0f / fmaxf((float)c, 1.0f);
        short8v o;
        #pragma unroll
        for (int k = 0; k < 8; ++k) o[k] = (short)f2bf_rne(res[k] * inv);
        *(short8v*)(meanH + (size_t)node * DD + li * 8) = o;
    }
}

// ===== MFMA SAGE layer: 512 thr / 128 rows / WTfrag in LDS / A prefetched ====
template <bool PROJ>
__global__ __launch_bounds__(512) void layer_mfma_kernel(
    const ushort* __restrict__ meanH, const ushort* __restrict__ rootH,
    const ushort* __restrict__ WTfrag, const float* __restrict__ bias,
    ushort* __restrict__ outH,
    const ushort* __restrict__ WoFrag, const float* __restrict__ bout,
    float* __restrict__ outF, int n) {
    __shared__ ushort sB[32768];                 // 64 KB
    const int tid = threadIdx.x;
    const int w = tid >> 6;                      // wave 0..7
    const int l = tid & 63;
    const int row0 = blockIdx.x * 128;
    const int lrow = w * 16 + (l & 15);
    const int kb = (l >> 4) * 8;
    const int lcol = l & 15;
    const int arowg = min(row0 + lrow, n - 1);

    const ushort* Am = meanH + (size_t)arowg * DD;
    const ushort* Ar = rootH + (size_t)arowg * DD;

    short8v ap[8];
    #pragma unroll
    for (int s = 0; s < 8; ++s) {
        ap[s] = (s < 4) ? *(const short8v*)(Am + s * 32 + kb)
                        : *(const short8v*)(Ar + (s - 4) * 32 + kb);
    }
    for (int i = tid; i < 4096; i += 512) {
        ((short8v*)sB)[i] = ((const short8v*)WTfrag)[i];
    }
    __syncthreads();

    f32x4 acc[8];
    #pragma unroll
    for (int t = 0; t < 8; ++t) acc[t] = (f32x4){0.f, 0.f, 0.f, 0.f};

    #pragma unroll
    for (int s = 0; s < 8; ++s) {
        #pragma unroll
        for (int t = 0; t < 8; ++t) {
            short8v bh = *(const short8v*)&sB[s * 4096 + t * 512 + l * 8];
            acc[t] = __builtin_amdgcn_mfma_f32_16x16x32_bf16(ap[s], bh, acc[t], 0, 0, 0);
        }
    }

    const int lrow0 = w * 16 + (l >> 4) * 4;
    if (!PROJ) {
        #pragma unroll
        for (int t = 0; t < 8; ++t) {
            const int col = t * 16 + lcol;
            const float b = bias[col];
            #pragma unroll
            for (int r = 0; r < 4; ++r) {
                int row = row0 + lrow0 + r;
                if (row < n)
                    outH[(size_t)row * DD + col] = f2bf_rne(fmaxf(acc[t][r] + b, 0.f));
            }
        }
    } else {
        __syncthreads();
        ushort (*sH)[136] = (ushort(*)[136])sB;
        #pragma unroll
        for (int t = 0; t < 8; ++t) {
            const int col = t * 16 + lcol;
            const float b = bias[col];
            #pragma unroll
            for (int r = 0; r < 4; ++r) {
                sH[lrow0 + r][col] = f2bf_rne(fmaxf(acc[t][r] + b, 0.f));
            }
        }
        f32x4 po[4];
        #pragma unroll
        for (int t = 0; t < 4; ++t) po[t] = (f32x4){0.f, 0.f, 0.f, 0.f};
        #pragma unroll
        for (int kc = 0; kc < 4; ++kc) {
            short8v ah = *(const short8v*)&sH[lrow][kc * 32 + kb];
            const ushort* fb = WoFrag + (size_t)kc * 2048 + l * 8;
            #pragma unroll
            for (int t = 0; t < 4; ++t) {
                short8v bh = *(const short8v*)(fb + t * 512);
                po[t] = __builtin_amdgcn_mfma_f32_16x16x32_bf16(ah, bh, po[t], 0, 0, 0);
            }
        }
        #pragma unroll
        for (int t = 0; t < 4; ++t) {
            const int col = t * 16 + lcol;
            const float b = bout[col];
            #pragma unroll
            for (int r = 0; r < 4; ++r) {
                int row = row0 + lrow0 + r;
                if (row < n) outF[(size_t)row * CC + col] = po[t][r] + b;
            }
        }
    }
}

extern "C" void kernel_launch(void* const* d_in, const int* in_sizes, int n_in,
                              void* d_out, int out_size, void* d_ws, size_t ws_size,
                              hipStream_t stream) {
    const float* x    = (const float*)d_in[0];
    const int*   ei   = (const int*)d_in[1];
    const float* W1l  = (const float*)d_in[2];
    const float* b1   = (const float*)d_in[3];
    const float* W1r  = (const float*)d_in[4];
    const float* W2l  = (const float*)d_in[5];
    const float* b2   = (const float*)d_in[6];
    const float* W2r  = (const float*)d_in[7];
    const float* Wout = (const float*)d_in[8];
    const float* bout = (const float*)d_in[9];
    float* out = (float*)d_out;
    const int n = in_sizes[0] / DD;       // 100000
    const int E = in_sizes[1] / 2;        // 1600000
    const size_t NP = (size_t)n * DD;

    const int NBUCK = (n + BKW - 1) / BKW;

    // workspace layout (~97 MB); ebuf (6.4MB) aliases the front of xq (12.8MB):
    // ebuf is dead after binB2; prep (which writes xq) runs after binB2.
    int* offs  = (int*)d_ws;                              // 100352 (incl offs[n])
    int* bcnt  = offs + 100352;                           // 256
    int* boffs = bcnt + 256;                              // 257 (pad 512)
    int* bcur  = boffs + 512;                             // 256
    int* csr   = bcur + 256;                              // E (pad)
    uint* ebuf = (uint*)(csr + 1600256);                  // E packed words
    uint* xq   = ebuf;                                    // n*128 fp8 bytes (12.8MB)
    ushort* xh = (ushort*)((uchar*)xq + NP);              // n*128 bf16
    ushort* meanH = xh + NP;                              // n*128 bf16
    ushort* h1h = meanH + NP;                             // n*128 bf16
    ushort* WTfrag1 = h1h + NP;                           // 32768 ushorts each
    ushort* WTfrag2 = WTfrag1 + 32768;
    ushort* WoFrag  = WTfrag2 + 32768;                    // 8192 ushorts

    hipMemsetAsync(bcnt, 0, sizeof(int) * 256, stream);
    bucket_cnt_kernel<<<(E + 8191) / 8192, 256, 0, stream>>>(ei, bcnt, E);
    bucket_scan_kernel<<<1, 256, 0, stream>>>(bcnt, boffs, bcur);
    binA_kernel<<<(E + NPB - 1) / NPB, 256, 0, stream>>>(ei, bcur, ebuf, E);
    binB2_kernel<<<NBUCK, 256, 0, stream>>>(ebuf, boffs, offs, csr, n);

    const int nxblk = (int)(NP / 8 / 256);    // 6250
    prep_kernel<<<nxblk + 36, 256, 0, stream>>>(x, xh, xq, W1l, W1r, W2l, W2r,
                                                Wout, WTfrag1, WTfrag2, WoFrag, nxblk);

    const int nblk = (n + 127) / 128;
    const int ablk = (n + 3) / 4;

    csr_agg8_kernel<<<ablk, 256, 0, stream>>>(xq, offs, csr, meanH, n);
    layer_mfma_kernel<false><<<nblk, 512, 0, stream>>>(
        meanH, xh, WTfrag1, b1, h1h,
        (const ushort*)nullptr, (const float*)nullptr, (float*)nullptr, n);

    csr_agg4_kernel<<<ablk, 256, 0, stream>>>(h1h, offs, csr, meanH, n);
    layer_mfma_kernel<true><<<nblk, 512, 0, stream>>>(
        meanH, h1h, WTfrag2, b2, (ushort*)nullptr,
        WoFrag, bout, out, n);
}

// Round 17
// 224.098 us; speedup vs baseline: 1.3554x; 1.0428x over previous
//
#include <hip/hip_runtime.h>
#include <hip/hip_fp8.h>

#define DD 128
#define CC 64
#define BKW 512            // nodes per bucket
#define NPB 4096           // edges per phase-B block

typedef __attribute__((ext_vector_type(8))) short short8v;
typedef __attribute__((ext_vector_type(4))) float f32x4;
typedef __attribute__((ext_vector_type(2))) float f32x2;

static __device__ inline ushort f2bf_rne(float f) {
    unsigned u = __float_as_uint(f);
    unsigned r = (u + 0x7FFFu + ((u >> 16) & 1u)) >> 16;
    return (ushort)r;
}
static __device__ inline float bf2f(ushort h) {
    return __uint_as_float(((unsigned)h) << 16);
}
static __device__ inline float bflo(uint u) {
    return __uint_as_float(u << 16);
}
static __device__ inline float bfhi(uint u) {
    return __uint_as_float(u & 0xffff0000u);
}

// ============ bucket histogram: per-block LDS hist, 256 global atomics ======
__global__ __launch_bounds__(256) void bucket_cnt_kernel(const int* __restrict__ ei,
                                                         int* __restrict__ bcnt, int E) {
    __shared__ int h[256];
    const int t = threadIdx.x;
    h[t] = 0;
    __syncthreads();
    const int base = blockIdx.x * 8192;
    const int end = min(E, base + 8192);
    for (int j = base + t; j < end; j += 256) {
        atomicAdd(&h[ei[E + j] >> 9], 1);
    }
    __syncthreads();
    if (h[t]) atomicAdd(&bcnt[t], h[t]);
}

// ============ bucket scan (256 entries, 1 block) -> boffs[257], bcur ========
__global__ __launch_bounds__(256) void bucket_scan_kernel(const int* __restrict__ bcnt,
                                                          int* __restrict__ boffs,
                                                          int* __restrict__ bcur) {
    __shared__ int s[256];
    const int t = threadIdx.x;
    int v = bcnt[t];
    s[t] = v;
    __syncthreads();
    for (int off = 1; off < 256; off <<= 1) {
        int xv = 0;
        if (t >= off) xv = s[t - off];
        __syncthreads();
        if (t >= off) s[t] += xv;
        __syncthreads();
    }
    int excl = s[t] - v;
    boffs[t] = excl;
    bcur[t] = excl;
    if (t == 255) boffs[256] = s[255];
}

// ===== phase B: bin edges by bucket; packed word = src | (dst&511)<<17 ======
// bucket id (0..195, 8 bits) in a separate byte array (R14 lesson).
__global__ __launch_bounds__(256) void binA_kernel(const int* __restrict__ ei,
                                                   int* __restrict__ bcur,
                                                   uint* __restrict__ ebuf, int E) {
    __shared__ int sRun[256];
    __shared__ int sRel[256];
    __shared__ int sBase[256];
    __shared__ uint sPair[NPB];
    __shared__ unsigned char sBkt[NPB];
    __shared__ int sHist[256];
    const int t = threadIdx.x;
    const int e0 = blockIdx.x * NPB;
    const int cntE = min(NPB, E - e0);

    sHist[t] = 0;
    __syncthreads();
    for (int j = t; j < cntE; j += 256) {
        int dst = ei[E + e0 + j];
        atomicAdd(&sHist[dst >> 9], 1);
    }
    __syncthreads();
    int h = sHist[t];
    sRun[t] = h;
    __syncthreads();
    for (int off = 1; off < 256; off <<= 1) {
        int v = 0;
        if (t >= off) v = sRun[t - off];
        __syncthreads();
        if (t >= off) sRun[t] += v;
        __syncthreads();
    }
    int runstart = sRun[t] - h;
    int base = 0;
    if (h > 0) base = atomicAdd(&bcur[t], h);
    sRun[t] = runstart;
    sRel[t] = runstart;
    sBase[t] = base;
    __syncthreads();
    for (int j = t; j < cntE; j += 256) {
        int src = ei[e0 + j];
        int dst = ei[E + e0 + j];
        int b = dst >> 9;
        int slot = atomicAdd(&sRel[b], 1);
        sPair[slot] = (uint)src | ((uint)(dst & 511) << 17);
        sBkt[slot] = (unsigned char)b;
    }
    __syncthreads();
    for (int s = t; s < cntE; s += 256) {
        uint p = sPair[s];
        int b = (int)sBkt[s];
        int gpos = sBase[b] + (s - sRun[b]);
        ebuf[gpos] = p;
    }
}

// ====== phase C: per-bucket: derive per-node offs in LDS, then scatter =====
// cnt array eliminated: cnt[i] == offs[i+1]-offs[i]; last block writes offs[n]=E.
__global__ __launch_bounds__(256) void binB2_kernel(const uint* __restrict__ ebuf,
                                                    const int* __restrict__ boffs,
                                                    int* __restrict__ offs,
                                                    int* __restrict__ csr, int n) {
    __shared__ int sCnt[BKW];
    __shared__ int sOffs[BKW];
    __shared__ int sScan[256];
    const int t = threadIdx.x;
    const int node0 = blockIdx.x * BKW;
    const int node1 = min(n, node0 + BKW);
    const int start = boffs[blockIdx.x];
    const int end = boffs[blockIdx.x + 1];

    sCnt[t] = 0; sCnt[t + 256] = 0;
    __syncthreads();
    for (int j = start + t; j < end; j += 256) {
        int d = (int)(ebuf[j] >> 17);
        atomicAdd(&sCnt[d], 1);
    }
    __syncthreads();
    int v0 = sCnt[2 * t], v1 = sCnt[2 * t + 1];
    int sum = v0 + v1;
    sScan[t] = sum;
    __syncthreads();
    for (int off = 1; off < 256; off <<= 1) {
        int xv = 0;
        if (t >= off) xv = sScan[t - off];
        __syncthreads();
        if (t >= off) sScan[t] += xv;
        __syncthreads();
    }
    int excl = sScan[t] - sum;
    sOffs[2 * t] = start + excl;
    sOffs[2 * t + 1] = start + excl + v0;
    __syncthreads();
    for (int i = t; i < BKW; i += 256) {
        int node = node0 + i;
        if (node < n) offs[node] = sOffs[i];
    }
    if (node1 == n && t == 0) offs[n] = end;
    __syncthreads();
    sCnt[t] = 0; sCnt[t + 256] = 0;
    __syncthreads();
    for (int j = start + t; j < end; j += 256) {
        uint p = ebuf[j];
        int d = (int)(p >> 17);
        int r = atomicAdd(&sCnt[d], 1);
        csr[sOffs[d] + r] = (int)(p & 0x1FFFFu);
    }
}

// ===== merged prep: x -> (xh bf16, xq e4m3) + wfrag + wofrag ===============
__global__ __launch_bounds__(256) void prep_kernel(
    const float* __restrict__ x, ushort* __restrict__ xh, uint* __restrict__ xq,
    const float* __restrict__ Wl1, const float* __restrict__ Wr1,
    const float* __restrict__ Wl2, const float* __restrict__ Wr2,
    const float* __restrict__ Wout,
    ushort* __restrict__ WTfrag1, ushort* __restrict__ WTfrag2,
    ushort* __restrict__ WoFrag, int nxblk) {
    const int t = threadIdx.x;
    const int bx = blockIdx.x;
    if (bx < nxblk) {
        int i = bx * 256 + t;                    // 8 elems per thread
        float4 a = ((const float4*)x)[2 * i];
        float4 b = ((const float4*)x)[2 * i + 1];
        float vv[8] = {a.x, a.y, a.z, a.w, b.x, b.y, b.z, b.w};
        ushort r[8];
        uint q[8];
        #pragma unroll
        for (int j = 0; j < 8; ++j) {
            r[j] = f2bf_rne(vv[j]);
            q[j] = (uint)__hip_fp8_e4m3(vv[j]).__x;
        }
        uint4 o;
        o.x = (uint)r[0] | ((uint)r[1] << 16);
        o.y = (uint)r[2] | ((uint)r[3] << 16);
        o.z = (uint)r[4] | ((uint)r[5] << 16);
        o.w = (uint)r[6] | ((uint)r[7] << 16);
        ((uint4*)xh)[i] = o;
        uint2 oq;
        oq.x = q[0] | (q[1] << 8) | (q[2] << 16) | (q[3] << 24);
        oq.y = q[4] | (q[5] << 8) | (q[6] << 16) | (q[7] << 24);
        ((uint2*)xq)[i] = oq;
    } else if (bx < nxblk + 32) {
        int li = bx - nxblk;
        int layer = li >> 4;
        int idx = (li & 15) * 256 + t;           // [0, 4096)
        const float* Wl = layer ? Wl2 : Wl1;
        const float* Wr = layer ? Wr2 : Wr1;
        ushort* dst = (layer ? WTfrag2 : WTfrag1) + (size_t)idx * 8;
        int lane = idx & 63, tt = (idx >> 6) & 7, s = idx >> 9;
        int col = tt * 16 + (lane & 15);
        int k0 = s * 32 + (lane >> 4) * 8;
        #pragma unroll
        for (int j = 0; j < 8; ++j) {
            int k = k0 + j;
            float v = (k < DD) ? Wl[k * DD + col] : Wr[(k - DD) * DD + col];
            dst[j] = f2bf_rne(v);
        }
    } else {
        int idx = (bx - nxblk - 32) * 256 + t;   // [0, 1024)
        ushort* dst = WoFrag + (size_t)idx * 8;
        int lane = idx & 63, tt = (idx >> 6) & 3, kc = idx >> 8;
        int col = tt * 16 + (lane & 15);
        int k0 = kc * 32 + (lane >> 4) * 8;
        #pragma unroll
        for (int j = 0; j < 8; ++j) {
            dst[j] = f2bf_rne(Wout[(k0 + j) * CC + col]);
        }
    }
}

// ====== CSR gather-aggregate, fp8 rows: 16 nbrs in flight ====
__global__ __launch_bounds__(256) void csr_agg8_kernel(
    const uint* __restrict__ xq, const int* __restrict__ offs,
    const int* __restrict__ csr, ushort* __restrict__ meanH, int n) {
    int node = blockIdx.x * 4 + (threadIdx.x >> 6);
    if (node >= n) return;
    const int lane = threadIdx.x & 63;
    const int sub = lane >> 4;
    const int li = lane & 15;
    const int start = offs[node];
    const int c = offs[node + 1] - start;
    f32x2 a[4], aa[4];
    #pragma unroll
    for (int k = 0; k < 4; ++k) { a[k] = (f32x2){0.f, 0.f}; aa[k] = (f32x2){0.f, 0.f}; }
    // row = 128 fp8 bytes; lane loads uint2 (8 dims)
    #define ACC8(A, U) { \
        A[0] += __builtin_amdgcn_cvt_pk_f32_fp8(U.x, false); \
        A[1] += __builtin_amdgcn_cvt_pk_f32_fp8(U.x, true);  \
        A[2] += __builtin_amdgcn_cvt_pk_f32_fp8(U.y, false); \
        A[3] += __builtin_amdgcn_cvt_pk_f32_fp8(U.y, true);  }
    const int c16 = c & ~15;
    int j = 0;
    if (c16 > 0) {
        int s0 = csr[start + sub];
        int s1 = csr[start + 4 + sub];
        int s2 = csr[start + 8 + sub];
        int s3 = csr[start + 12 + sub];
        for (; j < c16; j += 16) {
            int t0 = 0, t1 = 0, t2 = 0, t3 = 0;
            if (j + 16 < c16) {
                t0 = csr[start + j + 16 + sub];
                t1 = csr[start + j + 20 + sub];
                t2 = csr[start + j + 24 + sub];
                t3 = csr[start + j + 28 + sub];
            }
            uint2 u0 = *(const uint2*)((const uchar*)xq + (size_t)s0 * DD + li * 8);
            uint2 u1 = *(const uint2*)((const uchar*)xq + (size_t)s1 * DD + li * 8);
            uint2 u2 = *(const uint2*)((const uchar*)xq + (size_t)s2 * DD + li * 8);
            uint2 u3 = *(const uint2*)((const uchar*)xq + (size_t)s3 * DD + li * 8);
            ACC8(a, u0); ACC8(a, u1); ACC8(aa, u2); ACC8(aa, u3);
            s0 = t0; s1 = t1; s2 = t2; s3 = t3;
        }
    }
    if (c - j >= 8) {
        int s0 = csr[start + j + sub];
        int s1 = csr[start + j + 4 + sub];
        uint2 u0 = *(const uint2*)((const uchar*)xq + (size_t)s0 * DD + li * 8);
        uint2 u1 = *(const uint2*)((const uchar*)xq + (size_t)s1 * DD + li * 8);
        ACC8(a, u0); ACC8(aa, u1);
        j += 8;
    }
    if (c - j >= 4) {
        int s = csr[start + j + sub];
        uint2 u = *(const uint2*)((const uchar*)xq + (size_t)s * DD + li * 8);
        ACC8(a, u);
        j += 4;
    }
    if (j + sub < c) {
        int s = csr[start + j + sub];
        uint2 u = *(const uint2*)((const uchar*)xq + (size_t)s * DD + li * 8);
        ACC8(aa, u);
    }
    #undef ACC8
    float res[8];
    #pragma unroll
    for (int k = 0; k < 4; ++k) {
        f32x2 v = a[k] + aa[k];
        float e0 = v.x; e0 += __shfl_xor(e0, 16); e0 += __shfl_xor(e0, 32);
        float e1 = v.y; e1 += __shfl_xor(e1, 16); e1 += __shfl_xor(e1, 32);
        res[2 * k] = e0; res[2 * k + 1] = e1;
    }
    if (sub == 0) {
        float inv = 1.0f / fmaxf((float)c, 1.0f);
        short8v o;
        #pragma unroll
        for (int k = 0; k < 8; ++k) o[k] = (short)f2bf_rne(res[k] * inv);
        *(short8v*)(meanH + (size_t)node * DD + li * 8) = o;
    }
}

// ===== MFMA SAGE layer: 512 thr / 128 rows / WTfrag in LDS / A prefetched ====
// !PROJ: writes h1 as bf16 (outH) AND packed e4m3 bytes (outQ) for the fp8
// layer-2 gather. PROJ: fused 128->64 projection + bout, f32 out.
template <bool PROJ>
__global__ __launch_bounds__(512) void layer_mfma_kernel(
    const ushort* __restrict__ meanH, const ushort* __restrict__ rootH,
    const ushort* __restrict__ WTfrag, const float* __restrict__ bias,
    ushort* __restrict__ outH, uchar* __restrict__ outQ,
    const ushort* __restrict__ WoFrag, const float* __restrict__ bout,
    float* __restrict__ outF, int n) {
    __shared__ ushort sB[32768];                 // 64 KB
    const int tid = threadIdx.x;
    const int w = tid >> 6;                      // wave 0..7
    const int l = tid & 63;
    const int row0 = blockIdx.x * 128;
    const int lrow = w * 16 + (l & 15);
    const int kb = (l >> 4) * 8;
    const int lcol = l & 15;
    const int arowg = min(row0 + lrow, n - 1);

    const ushort* Am = meanH + (size_t)arowg * DD;
    const ushort* Ar = rootH + (size_t)arowg * DD;

    short8v ap[8];
    #pragma unroll
    for (int s = 0; s < 8; ++s) {
        ap[s] = (s < 4) ? *(const short8v*)(Am + s * 32 + kb)
                        : *(const short8v*)(Ar + (s - 4) * 32 + kb);
    }
    for (int i = tid; i < 4096; i += 512) {
        ((short8v*)sB)[i] = ((const short8v*)WTfrag)[i];
    }
    __syncthreads();

    f32x4 acc[8];
    #pragma unroll
    for (int t = 0; t < 8; ++t) acc[t] = (f32x4){0.f, 0.f, 0.f, 0.f};

    #pragma unroll
    for (int s = 0; s < 8; ++s) {
        #pragma unroll
        for (int t = 0; t < 8; ++t) {
            short8v bh = *(const short8v*)&sB[s * 4096 + t * 512 + l * 8];
            acc[t] = __builtin_amdgcn_mfma_f32_16x16x32_bf16(ap[s], bh, acc[t], 0, 0, 0);
        }
    }

    const int lrow0 = w * 16 + (l >> 4) * 4;
    if (!PROJ) {
        #pragma unroll
        for (int t = 0; t < 8; ++t) {
            const int col = t * 16 + lcol;
            const float b = bias[col];
            #pragma unroll
            for (int r = 0; r < 4; ++r) {
                int row = row0 + lrow0 + r;
                if (row < n) {
                    float o = fmaxf(acc[t][r] + b, 0.f);
                    outH[(size_t)row * DD + col] = f2bf_rne(o);
                    outQ[(size_t)row * DD + col] = __hip_fp8_e4m3(o).__x;
                }
            }
        }
    } else {
        __syncthreads();
        ushort (*sH)[136] = (ushort(*)[136])sB;
        #pragma unroll
        for (int t = 0; t < 8; ++t) {
            const int col = t * 16 + lcol;
            const float b = bias[col];
            #pragma unroll
            for (int r = 0; r < 4; ++r) {
                sH[lrow0 + r][col] = f2bf_rne(fmaxf(acc[t][r] + b, 0.f));
            }
        }
        f32x4 po[4];
        #pragma unroll
        for (int t = 0; t < 4; ++t) po[t] = (f32x4){0.f, 0.f, 0.f, 0.f};
        #pragma unroll
        for (int kc = 0; kc < 4; ++kc) {
            short8v ah = *(const short8v*)&sH[lrow][kc * 32 + kb];
            const ushort* fb = WoFrag + (size_t)kc * 2048 + l * 8;
            #pragma unroll
            for (int t = 0; t < 4; ++t) {
                short8v bh = *(const short8v*)(fb + t * 512);
                po[t] = __builtin_amdgcn_mfma_f32_16x16x32_bf16(ah, bh, po[t], 0, 0, 0);
            }
        }
        #pragma unroll
        for (int t = 0; t < 4; ++t) {
            const int col = t * 16 + lcol;
            const float b = bout[col];
            #pragma unroll
            for (int r = 0; r < 4; ++r) {
                int row = row0 + lrow0 + r;
                if (row < n) outF[(size_t)row * CC + col] = po[t][r] + b;
            }
        }
    }
}

extern "C" void kernel_launch(void* const* d_in, const int* in_sizes, int n_in,
                              void* d_out, int out_size, void* d_ws, size_t ws_size,
                              hipStream_t stream) {
    const float* x    = (const float*)d_in[0];
    const int*   ei   = (const int*)d_in[1];
    const float* W1l  = (const float*)d_in[2];
    const float* b1   = (const float*)d_in[3];
    const float* W1r  = (const float*)d_in[4];
    const float* W2l  = (const float*)d_in[5];
    const float* b2   = (const float*)d_in[6];
    const float* W2r  = (const float*)d_in[7];
    const float* Wout = (const float*)d_in[8];
    const float* bout = (const float*)d_in[9];
    float* out = (float*)d_out;
    const int n = in_sizes[0] / DD;       // 100000
    const int E = in_sizes[1] / 2;        // 1600000
    const size_t NP = (size_t)n * DD;

    const int NBUCK = (n + BKW - 1) / BKW;

    // workspace (~110 MB); ebuf (6.4MB) aliases the front of xq (12.8MB):
    // ebuf is dead after binB2; prep (which writes xq) runs after binB2.
    int* offs  = (int*)d_ws;                              // 100352 (incl offs[n])
    int* bcnt  = offs + 100352;                           // 256
    int* boffs = bcnt + 256;                              // 257 (pad 512)
    int* bcur  = boffs + 512;                             // 256
    int* csr   = bcur + 256;                              // E (pad)
    uint* ebuf = (uint*)(csr + 1600256);                  // E packed words
    uint* xq   = ebuf;                                    // n*128 fp8 (12.8MB)
    ushort* xh = (ushort*)((uchar*)xq + NP);              // n*128 bf16
    ushort* meanH = xh + NP;                              // n*128 bf16
    ushort* h1h = meanH + NP;                             // n*128 bf16
    ushort* WTfrag1 = h1h + NP;                           // 32768 ushorts each
    ushort* WTfrag2 = WTfrag1 + 32768;
    ushort* WoFrag  = WTfrag2 + 32768;                    // 8192 ushorts
    uchar* h1q = (uchar*)(WoFrag + 8192);                 // n*128 fp8 (12.8MB)

    hipMemsetAsync(bcnt, 0, sizeof(int) * 256, stream);
    bucket_cnt_kernel<<<(E + 8191) / 8192, 256, 0, stream>>>(ei, bcnt, E);
    bucket_scan_kernel<<<1, 256, 0, stream>>>(bcnt, boffs, bcur);
    binA_kernel<<<(E + NPB - 1) / NPB, 256, 0, stream>>>(ei, bcur, ebuf, E);
    binB2_kernel<<<NBUCK, 256, 0, stream>>>(ebuf, boffs, offs, csr, n);

    const int nxblk = (int)(NP / 8 / 256);    // 6250
    prep_kernel<<<nxblk + 36, 256, 0, stream>>>(x, xh, xq, W1l, W1r, W2l, W2r,
                                                Wout, WTfrag1, WTfrag2, WoFrag, nxblk);

    const int nblk = (n + 127) / 128;
    const int ablk = (n + 3) / 4;

    csr_agg8_kernel<<<ablk, 256, 0, stream>>>(xq, offs, csr, meanH, n);
    layer_mfma_kernel<false><<<nblk, 512, 0, stream>>>(
        meanH, xh, WTfrag1, b1, h1h, h1q,
        (const ushort*)nullptr, (const float*)nullptr, (float*)nullptr, n);

    csr_agg8_kernel<<<ablk, 256, 0, stream>>>((const uint*)h1q, offs, csr, meanH, n);
    layer_mfma_kernel<true><<<nblk, 512, 0, stream>>>(
        meanH, h1h, WTfrag2, b2, (ushort*)nullptr, (uchar*)nullptr,
        WoFrag, bout, out, n);
}